// Round 2
// baseline (819.241 us; speedup 1.0000x reference)
//
#include <hip/hip_runtime.h>
#include <hip/hip_bf16.h>
#include <math.h>

#define NEG_SLOPE 0.2f

__device__ __forceinline__ unsigned fenc(float f){
  unsigned u = __float_as_uint(f);
  return (u & 0x80000000u) ? ~u : (u | 0x80000000u);
}
__device__ __forceinline__ float fdec(unsigned u){
  return (u & 0x80000000u) ? __uint_as_float(u & 0x7fffffffu) : __uint_as_float(~u);
}
__device__ __forceinline__ float sigmoidf(float x){ return 1.f/(1.f+expf(-x)); }

// ============================ CSR build =====================================
__global__ void init_kernel(int* counts, int* gstart, int* gend, int n, int b){
  int i = blockIdx.x*blockDim.x + threadIdx.x;
  if (i < n) counts[i] = 0;
  if (i < b){ gstart[i] = n; gend[i] = 0; }
}

__global__ void build_kernel(const int* __restrict__ ei, const int* __restrict__ batch,
                             int* counts, int* gstart, int* gend, int E, int n){
  int i = blockIdx.x*blockDim.x + threadIdx.x;
  if (i < E) atomicAdd(&counts[ei[E+i]], 1);
  if (i < n){
    int b = batch[i];
    atomicMin(&gstart[b], i);
    atomicMax(&gend[b], i+1);
  }
}

__global__ void scan_kernel(const int* __restrict__ counts, int* offs, int* cursor, int n){
  const int T = 1024;
  int tid = threadIdx.x;
  int chunk = (n + T - 1)/T;
  int base = tid*chunk;
  int local = 0;
  for (int i=0;i<chunk;i++){ int idx=base+i; if (idx<n) local += counts[idx]; }
  __shared__ int ss[T];
  ss[tid]=local; __syncthreads();
  for (int off=1; off<T; off<<=1){
    int v = (tid>=off)? ss[tid-off] : 0;
    __syncthreads();
    ss[tid]+=v;
    __syncthreads();
  }
  int run = ss[tid]-local;  // exclusive prefix
  for (int i=0;i<chunk;i++){
    int idx=base+i;
    if (idx<n){ offs[idx]=run; cursor[idx]=run; run += counts[idx]; }
  }
  if (tid==T-1) offs[n]=run;
}

__global__ void fill_kernel(const int* __restrict__ ei, int* cursor, int* csr, int E){
  int i = blockIdx.x*blockDim.x + threadIdx.x;
  if (i<E){
    int dst = ei[E+i];
    int pos = atomicAdd(&cursor[dst],1);
    csr[pos] = ei[i];
  }
}

// ============================ fp32 tiled GEMM ===============================
// C[M,N] = A[M,K] @ B[K,N], row-major. BM=BN=128, BK=16, 256 threads,
// 8x8 per thread in split-4 layout: rows {ty*4+i, 64+ty*4+i}, cols
// {tx*4+j, 64+tx*4+j} -> all LDS reads are float4 at 16B stride (2-way = free).
__global__ __launch_bounds__(256) void gemm128(const float* __restrict__ A,
                                               const float* __restrict__ B,
                                               float* __restrict__ C,
                                               int M, int K, int N){
  __shared__ float As[16][128];
  __shared__ float Bs[16][128];
  int tid = threadIdx.x;
  int bm = blockIdx.x*128, bn = blockIdx.y*128;
  int ar = tid>>1, ak=(tid&1)*8;        // A: 128 rows x 16 k, 8 floats/thread
  int br = tid>>4, bc=(tid&15)*4;       // B: 16 rows x 128 cols, 2x float4/thread
  int ty = tid>>4, tx = tid&15;
  float acc[8][8] = {};
  for (int k0=0; k0<K; k0+=16){
    bool arv = (bm+ar) < M;
    float4 a0 = make_float4(0,0,0,0), a1 = make_float4(0,0,0,0);
    if (arv){
      const float* ap = A + (size_t)(bm+ar)*K + k0 + ak;
      a0 = *reinterpret_cast<const float4*>(ap);
      a1 = *reinterpret_cast<const float4*>(ap+4);
    }
    const float* bp = B + (size_t)(k0+br)*N + bn;
    float4 b0 = *reinterpret_cast<const float4*>(bp + bc);
    float4 b1 = *reinterpret_cast<const float4*>(bp + 64 + bc);
    As[ak+0][ar]=a0.x; As[ak+1][ar]=a0.y; As[ak+2][ar]=a0.z; As[ak+3][ar]=a0.w;
    As[ak+4][ar]=a1.x; As[ak+5][ar]=a1.y; As[ak+6][ar]=a1.z; As[ak+7][ar]=a1.w;
    *reinterpret_cast<float4*>(&Bs[br][bc])    = b0;
    *reinterpret_cast<float4*>(&Bs[br][64+bc]) = b1;
    __syncthreads();
    #pragma unroll
    for (int kk=0; kk<16; kk++){
      float4 av0 = *reinterpret_cast<float4*>(&As[kk][ty*4]);
      float4 av1 = *reinterpret_cast<float4*>(&As[kk][64+ty*4]);
      float4 bv0 = *reinterpret_cast<float4*>(&Bs[kk][tx*4]);
      float4 bv1 = *reinterpret_cast<float4*>(&Bs[kk][64+tx*4]);
      float a[8] = {av0.x,av0.y,av0.z,av0.w, av1.x,av1.y,av1.z,av1.w};
      float b[8] = {bv0.x,bv0.y,bv0.z,bv0.w, bv1.x,bv1.y,bv1.z,bv1.w};
      #pragma unroll
      for (int i=0;i<8;i++)
        #pragma unroll
        for (int j=0;j<8;j++)
          acc[i][j] += a[i]*b[j];
    }
    __syncthreads();
  }
  #pragma unroll
  for (int i=0;i<8;i++){
    int row = bm + (i<4 ? ty*4+i : 64+ty*4+(i-4));
    if (row < M){
      float* cp = C + (size_t)row*N + bn;
      *reinterpret_cast<float4*>(cp + tx*4)    = make_float4(acc[i][0],acc[i][1],acc[i][2],acc[i][3]);
      *reinterpret_cast<float4*>(cp + 64+tx*4) = make_float4(acc[i][4],acc[i][5],acc[i][6],acc[i][7]);
    }
  }
}

// ============== per-node attention logits s,d = <h, a_src/a_dst> ============
template<int H, int C>
__global__ void sd_kernel(const float* __restrict__ h, const float* __restrict__ asrc,
                          const float* __restrict__ adst, float* __restrict__ s,
                          float* __restrict__ d, int n_nodes){
  int wave = threadIdx.x >> 6, lane = threadIdx.x & 63;
  int n = blockIdx.x*4 + wave;
  if (n >= n_nodes) return;
  const float* hn = h + (size_t)n*H*C;
  #pragma unroll
  for (int hd=0; hd<H; ++hd){
    float ps=0.f, pd=0.f;
    for (int c=lane; c<C; c+=64){
      float v = hn[hd*C+c];
      ps += v*asrc[hd*C+c];
      pd += v*adst[hd*C+c];
    }
    #pragma unroll
    for (int off=32; off; off>>=1){ ps += __shfl_down(ps,off); pd += __shfl_down(pd,off); }
    if (lane==0){ s[n*H+hd]=ps; d[n*H+hd]=pd; }
  }
}

// ================= GAT aggregation: softmax over in-edges ====================
template<int H, int C>
__global__ __launch_bounds__(256) void agg_kernel(
    const float* __restrict__ hbuf, const float* __restrict__ s,
    const float* __restrict__ d, const int* __restrict__ offs,
    const int* __restrict__ csr, const float* __restrict__ bias,
    float* __restrict__ y, int n_nodes){
  constexpr int HC = H*C;
  int n = blockIdx.x;
  int tid = threadIdx.x;
  __shared__ float sdst[H];
  __shared__ float sm[H];
  __shared__ float sl[H];
  __shared__ float wred[4*H];
  __shared__ float sw[64*H];
  __shared__ int ssrc[64];
  if (tid < H) sdst[tid] = d[n*H+tid];
  int start = offs[n];
  int cnt = offs[n+1]-start;
  int cnt1 = cnt+1;                      // + self loop
  __syncthreads();
  float mx[H];
  #pragma unroll
  for (int h=0;h<H;h++) mx[h] = -1e30f;
  for (int i=tid; i<cnt1; i+=256){
    int src = (i==cnt) ? n : csr[start+i];
    #pragma unroll
    for (int h=0;h<H;h++){
      float e = s[src*H+h] + sdst[h];
      e = e>=0.f ? e : NEG_SLOPE*e;
      mx[h] = fmaxf(mx[h], e);
    }
  }
  #pragma unroll
  for (int off=32; off; off>>=1)
    #pragma unroll
    for (int h=0;h<H;h++) mx[h] = fmaxf(mx[h], __shfl_down(mx[h],off));
  int wave = tid>>6, lane = tid&63;
  if (lane==0)
    #pragma unroll
    for (int h=0;h<H;h++) wred[wave*H+h]=mx[h];
  __syncthreads();
  if (tid < H){
    float m = wred[tid];
    for (int w=1;w<4;w++) m = fmaxf(m, wred[w*H+tid]);
    sm[tid]=m;
  }
  __syncthreads();
  float acc = 0.f;
  float lp[H];
  #pragma unroll
  for (int h=0;h<H;h++) lp[h]=0.f;
  int c = tid;
  int head = (tid < HC) ? (c / C) : 0;
  for (int base=0; base<cnt1; base+=64){
    int nchunk = min(64, cnt1-base);
    if (tid < nchunk){
      int i = base+tid;
      int src = (i==cnt) ? n : csr[start+i];
      ssrc[tid]=src;
      #pragma unroll
      for (int h=0;h<H;h++){
        float e = s[src*H+h] + sdst[h];
        e = e>=0.f ? e : NEG_SLOPE*e;
        float w = expf(e - sm[h]);
        sw[tid*H+h]=w;
        lp[h]+=w;
      }
    }
    __syncthreads();
    if (tid < HC){
      for (int j=0;j<nchunk;j++){
        acc += sw[j*H+head] * hbuf[(size_t)ssrc[j]*HC + c];
      }
    }
    __syncthreads();
  }
  if (wave==0){
    #pragma unroll
    for (int off=32; off; off>>=1)
      #pragma unroll
      for (int h=0;h<H;h++) lp[h] += __shfl_down(lp[h],off);
    if (lane==0)
      #pragma unroll
      for (int h=0;h<H;h++) sl[h]=lp[h];
  }
  __syncthreads();
  if (tid < HC){
    float o = acc/(sl[head]+1e-16f) + bias[c];
    y[(size_t)n*HC+c] = o>0.f ? o : expm1f(o);
  }
}

// ======================= Set2Set, grid-parallel =============================
__global__ void s2s_init(float* qstar, float* hc, unsigned* menc, int B){
  int i = blockIdx.x*blockDim.x + threadIdx.x;
  if (i < B*256) qstar[i] = 0.f;
  if (i < 2*B*128) hc[i] = 0.f;
  if (i < 3*B) menc[i] = 0u;
}

__global__ __launch_bounds__(256) void lstm_kernel(
    const float* __restrict__ qstar, float* __restrict__ hc,
    const float* __restrict__ Wih, const float* __restrict__ Whh,
    const float* __restrict__ bih, const float* __restrict__ bhh,
    float* __restrict__ q, int B){
  int b = blockIdx.x, tid = threadIdx.x;
  __shared__ float qs[256], hs[128], gsh[512];
  float* hst = hc + (size_t)b*128;
  float* cst = hc + (size_t)(B + b)*128;
  qs[tid] = qstar[b*256+tid];
  if (tid < 128) hs[tid] = hst[tid];
  __syncthreads();
  #pragma unroll
  for (int p=0;p<2;p++){
    int j = tid + p*256;
    float a = bih[j] + bhh[j];
    const float* wi = Wih + (size_t)j*256;
    for (int k=0;k<256;k+=4)
      a += qs[k]*wi[k] + qs[k+1]*wi[k+1] + qs[k+2]*wi[k+2] + qs[k+3]*wi[k+3];
    const float* wh = Whh + (size_t)j*128;
    for (int k=0;k<128;k+=4)
      a += hs[k]*wh[k] + hs[k+1]*wh[k+1] + hs[k+2]*wh[k+2] + hs[k+3]*wh[k+3];
    gsh[j] = a;
  }
  __syncthreads();
  if (tid < 128){
    float ig = sigmoidf(gsh[tid]);
    float fg = sigmoidf(gsh[128+tid]);
    float gg = tanhf(gsh[256+tid]);
    float og = sigmoidf(gsh[384+tid]);
    float c2 = fg*cst[tid] + ig*gg;
    cst[tid] = c2;
    float h2 = og*tanhf(c2);
    hst[tid] = h2;
    q[b*128+tid] = h2;
  }
}

// e[i] = <x[i], q[batch[i]]>; per-graph running max via encoded atomicMax.
__global__ __launch_bounds__(256) void e_kernel(
    const float* __restrict__ x, const float* __restrict__ q,
    const int* __restrict__ batch, float* __restrict__ e,
    unsigned* __restrict__ menc, int N){
  int tid = threadIdx.x;
  int wave = tid>>6, lane = tid&63;
  int base = blockIdx.x*16;
  __shared__ unsigned lm[64];
  if (tid < 64) lm[tid] = 0u;
  __syncthreads();
  #pragma unroll
  for (int j=0;j<4;j++){
    int i = base + wave*4 + j;
    if (i < N){
      int g = batch[i];
      float2 xv = *reinterpret_cast<const float2*>(x + (size_t)i*128 + lane*2);
      float2 qv = *reinterpret_cast<const float2*>(q + (size_t)g*128 + lane*2);
      float p = xv.x*qv.x + xv.y*qv.y;
      #pragma unroll
      for (int off=32; off; off>>=1) p += __shfl_down(p, off);
      if (lane==0){
        e[i] = p;
        atomicMax(&lm[g], fenc(p));
      }
    }
  }
  __syncthreads();
  if (tid < 64 && lm[tid]) atomicMax(&menc[tid], lm[tid]);
}

// r_g[c] = sum_i exp(e_i-m) x[i,c] / (sum_i exp(e_i-m) + 1e-16); write qstar.
__global__ __launch_bounds__(256) void r_kernel(
    const float* __restrict__ x, const float* __restrict__ e,
    const unsigned* __restrict__ menc, const int* __restrict__ gstart,
    const int* __restrict__ gend, const float* __restrict__ q,
    float* __restrict__ qstar){
  int b = blockIdx.x, tid = threadIdx.x;
  int start = gstart[b], end = gend[b];
  float m = fdec(menc[b]);
  int col = tid & 127, half = tid >> 7;
  float rc = 0.f, lsum = 0.f;
  for (int i=start+half; i<end; i+=2){
    float w = expf(e[i]-m);
    rc += w * x[(size_t)i*128 + col];
    if (col==0) lsum += w;
  }
  __shared__ float rsh[256];
  __shared__ float ls[2];
  ls[0]=0.f; ls[1]=0.f;
  __syncthreads();
  rsh[tid] = rc;
  if (col==0) ls[half] = lsum;
  __syncthreads();
  if (tid < 128){
    float r = (rsh[tid]+rsh[tid+128]) / (ls[0]+ls[1]+1e-16f);
    qstar[b*256+tid] = q[b*128+tid];
    qstar[b*256+128+tid] = r;
  }
}

__global__ __launch_bounds__(256) void scorer_kernel(
    const float* __restrict__ qstar, const float* __restrict__ gfeat,
    const float* __restrict__ gW1, const float* __restrict__ gb1,
    const float* __restrict__ gW2, const float* __restrict__ gb2,
    const float* __restrict__ mW1, const float* __restrict__ mb1,
    const float* __restrict__ mW2, const float* __restrict__ mb2,
    float* __restrict__ out){
  int b = blockIdx.x, tid = threadIdx.x;
  __shared__ float z[288], gf1[64], hid[128];
  z[tid] = qstar[b*256+tid];
  if (tid < 64){
    float a = gb1[tid];
    for (int k=0;k<9;k++) a += gfeat[b*9+k]*gW1[k*64+tid];
    gf1[tid] = a>0.f ? a : 0.f;
  }
  __syncthreads();
  if (tid < 32){
    float a = gb2[tid];
    for (int k=0;k<64;k++) a += gf1[k]*gW2[k*32+tid];
    z[256+tid] = a;
  }
  __syncthreads();
  if (tid < 128){
    float a = mb1[tid];
    for (int k=0;k<288;k++) a += z[k]*mW1[(size_t)k*128+tid];
    hid[tid] = a>0.f ? a : 0.f;
  }
  __syncthreads();
  if (tid < 4){
    float a = mb2[tid];
    for (int k=0;k<128;k++) a += hid[k]*mW2[k*4+tid];
    out[b*4+tid] = a;
  }
}

// ================================ launch ====================================
extern "C" void kernel_launch(void* const* d_in, const int* in_sizes, int n_in,
                              void* d_out, int out_size, void* d_ws, size_t ws_size,
                              hipStream_t stream) {
  const float* x     = (const float*)d_in[0];
  const int*   ei    = (const int*)d_in[1];
  const int*   batch = (const int*)d_in[2];
  const float* gfeat = (const float*)d_in[3];
  const float* W1    = (const float*)d_in[4];
  const float* as1   = (const float*)d_in[5];
  const float* ad1   = (const float*)d_in[6];
  const float* b1    = (const float*)d_in[7];
  const float* W2    = (const float*)d_in[8];
  const float* as2   = (const float*)d_in[9];
  const float* ad2   = (const float*)d_in[10];
  const float* b2    = (const float*)d_in[11];
  const float* W3    = (const float*)d_in[12];
  const float* as3   = (const float*)d_in[13];
  const float* ad3   = (const float*)d_in[14];
  const float* b3    = (const float*)d_in[15];
  const float* Wih   = (const float*)d_in[16];
  const float* Whh   = (const float*)d_in[17];
  const float* bih   = (const float*)d_in[18];
  const float* bhh   = (const float*)d_in[19];
  const float* gW1   = (const float*)d_in[20];
  const float* gb1   = (const float*)d_in[21];
  const float* gW2   = (const float*)d_in[22];
  const float* gb2   = (const float*)d_in[23];
  const float* mW1   = (const float*)d_in[24];
  const float* mb1   = (const float*)d_in[25];
  const float* mW2   = (const float*)d_in[26];
  const float* mb2   = (const float*)d_in[27];

  const int N = in_sizes[0]/128;   // 20000
  const int E = in_sizes[1]/2;     // 320000
  const int B = in_sizes[3]/9;     // 64

  char* ws = (char*)d_ws;
  size_t off = 0;
  auto alloc = [&](size_t bytes)->char*{
    char* p = ws + off;
    off += (bytes + 255) & ~(size_t)255;
    return p;
  };
  float* hbuf   = (float*)alloc((size_t)N*256*4);
  float* ybuf1  = (float*)alloc((size_t)N*256*4);
  float* ybuf2  = (float*)alloc((size_t)N*256*4);
  float* sbuf   = (float*)alloc((size_t)N*4*4);
  float* dbuf   = (float*)alloc((size_t)N*4*4);
  float* e_ws   = (float*)alloc((size_t)N*4);
  int*   counts = (int*)alloc((size_t)N*4);
  int*   offs   = (int*)alloc((size_t)(N+1)*4);
  int*   cursor = (int*)alloc((size_t)N*4);
  int*   csr    = (int*)alloc((size_t)E*4);
  int*   gstart = (int*)alloc((size_t)B*4);
  int*   gend   = (int*)alloc((size_t)B*4);
  float* qstar  = (float*)alloc((size_t)B*256*4);
  float* hcbuf  = (float*)alloc((size_t)2*B*128*4);
  float* qbuf   = (float*)alloc((size_t)B*128*4);
  unsigned* menc= (unsigned*)alloc((size_t)3*B*4);

  int gridEN = (max(E,N)+255)/256;
  init_kernel<<<(max(N,B)+255)/256, 256, 0, stream>>>(counts, gstart, gend, N, B);
  build_kernel<<<gridEN, 256, 0, stream>>>(ei, batch, counts, gstart, gend, E, N);
  scan_kernel<<<1, 1024, 0, stream>>>(counts, offs, cursor, N);
  fill_kernel<<<(E+255)/256, 256, 0, stream>>>(ei, cursor, csr, E);

  int gm = (N+127)/128;
  // ---- layer 1: x[N,128] -> h[N,256] -> y1
  gemm128<<<dim3(gm,2), 256, 0, stream>>>(x, W1, hbuf, N, 128, 256);
  sd_kernel<4,64><<<(N+3)/4, 256, 0, stream>>>(hbuf, as1, ad1, sbuf, dbuf, N);
  agg_kernel<4,64><<<N, 256, 0, stream>>>(hbuf, sbuf, dbuf, offs, csr, b1, ybuf1, N);
  // ---- layer 2: y1[N,256] -> h[N,256] -> y2
  gemm128<<<dim3(gm,2), 256, 0, stream>>>(ybuf1, W2, hbuf, N, 256, 256);
  sd_kernel<4,64><<<(N+3)/4, 256, 0, stream>>>(hbuf, as2, ad2, sbuf, dbuf, N);
  agg_kernel<4,64><<<N, 256, 0, stream>>>(hbuf, sbuf, dbuf, offs, csr, b2, ybuf2, N);
  // ---- layer 3: y2[N,256] -> h[N,128] -> y1 (reuse)
  gemm128<<<dim3(gm,1), 256, 0, stream>>>(ybuf2, W3, hbuf, N, 256, 128);
  sd_kernel<1,128><<<(N+3)/4, 256, 0, stream>>>(hbuf, as3, ad3, sbuf, dbuf, N);
  agg_kernel<1,128><<<N, 256, 0, stream>>>(hbuf, sbuf, dbuf, offs, csr, b3, ybuf1, N);
  // ---- set2set (grid-parallel) ----
  s2s_init<<<(B*256+255)/256, 256, 0, stream>>>(qstar, hcbuf, menc, B);
  for (int step=0; step<3; ++step){
    lstm_kernel<<<B, 256, 0, stream>>>(qstar, hcbuf, Wih, Whh, bih, bhh, qbuf, B);
    e_kernel<<<(N+15)/16, 256, 0, stream>>>(ybuf1, qbuf, batch, e_ws, menc + step*B, N);
    r_kernel<<<B, 256, 0, stream>>>(ybuf1, e_ws, menc + step*B, gstart, gend, qbuf, qstar);
  }
  scorer_kernel<<<B, 256, 0, stream>>>(qstar, gfeat, gW1, gb1, gW2, gb2,
                                       mW1, mb1, mW2, mb2, (float*)d_out);
}

// Round 3
// 643.016 us; speedup vs baseline: 1.2741x; 1.2741x over previous
//
#include <hip/hip_runtime.h>
#include <hip/hip_bf16.h>
#include <math.h>

#define NEG_SLOPE 0.2f

__device__ __forceinline__ float sigmoidf(float x){ return 1.f/(1.f+expf(-x)); }

// ============================ CSR build =====================================
__global__ void init_kernel(int* counts, int* gstart, int* gend, int n, int b){
  int i = blockIdx.x*blockDim.x + threadIdx.x;
  if (i < n) counts[i] = 0;
  if (i < b){ gstart[i] = 0; gend[i] = 0; }
}

// counts via atomics (16-way mean contention); graph bounds via sorted-batch
// boundary detection (NO atomics - the 64-address atomicMin/Max chains were
// 122us in round 2).
__global__ void build_kernel(const int* __restrict__ ei, const int* __restrict__ batch,
                             int* counts, int* gstart, int* gend, int E, int n){
  int i = blockIdx.x*blockDim.x + threadIdx.x;
  if (i < E) atomicAdd(&counts[ei[E+i]], 1);
  if (i < n){
    int b = batch[i];
    if (i == 0 || batch[i-1] != b) gstart[b] = i;
    if (i == n-1 || batch[i+1] != b) gend[b] = i+1;
  }
}

__global__ void scan_kernel(const int* __restrict__ counts, int* offs, int* cursor, int n){
  const int T = 1024;
  int tid = threadIdx.x;
  int chunk = (n + T - 1)/T;
  int base = tid*chunk;
  int local = 0;
  for (int i=0;i<chunk;i++){ int idx=base+i; if (idx<n) local += counts[idx]; }
  __shared__ int ss[T];
  ss[tid]=local; __syncthreads();
  for (int off=1; off<T; off<<=1){
    int v = (tid>=off)? ss[tid-off] : 0;
    __syncthreads();
    ss[tid]+=v;
    __syncthreads();
  }
  int run = ss[tid]-local;  // exclusive prefix
  for (int i=0;i<chunk;i++){
    int idx=base+i;
    if (idx<n){ offs[idx]=run; cursor[idx]=run; run += counts[idx]; }
  }
  if (tid==T-1) offs[n]=run;
}

__global__ void fill_kernel(const int* __restrict__ ei, int* cursor, int* csr, int E){
  int i = blockIdx.x*blockDim.x + threadIdx.x;
  if (i<E){
    int dst = ei[E+i];
    int pos = atomicAdd(&cursor[dst],1);
    csr[pos] = ei[i];
  }
}

// ============================ fp32 tiled GEMM ===============================
// C[M,N] = A[M,K] @ B[K,N], row-major. BM=64, BN=128, BK=16, 256 threads,
// 4x8 micro-tile with split-4 cols -> float4 LDS reads, 2-way aliasing (free).
__global__ __launch_bounds__(256) void gemm64x128(const float* __restrict__ A,
                                                  const float* __restrict__ B,
                                                  float* __restrict__ C,
                                                  int M, int K, int N){
  __shared__ float As[16][64];
  __shared__ float Bs[16][128];
  int tid = threadIdx.x;
  int bm = blockIdx.x*64, bn = blockIdx.y*128;
  int ar = tid>>2, ak=(tid&3)*4;        // A: 64 rows x 16 k, float4/thread
  int br = tid>>4, bc=(tid&15)*8;       // B: 16 rows x 128 cols, 8 floats/thread
  int ty = tid>>4, tx = tid&15;
  float acc[4][8] = {};
  for (int k0=0; k0<K; k0+=16){
    float4 av = make_float4(0,0,0,0);
    if (bm+ar < M) av = *reinterpret_cast<const float4*>(A + (size_t)(bm+ar)*K + k0 + ak);
    const float* bp = B + (size_t)(k0+br)*N + bn + bc;
    float4 b0 = *reinterpret_cast<const float4*>(bp);
    float4 b1 = *reinterpret_cast<const float4*>(bp+4);
    As[ak+0][ar]=av.x; As[ak+1][ar]=av.y; As[ak+2][ar]=av.z; As[ak+3][ar]=av.w;
    *reinterpret_cast<float4*>(&Bs[br][bc])   = b0;
    *reinterpret_cast<float4*>(&Bs[br][bc+4]) = b1;
    __syncthreads();
    #pragma unroll
    for (int kk=0; kk<16; kk++){
      float4 av0 = *reinterpret_cast<float4*>(&As[kk][ty*4]);
      float4 bv0 = *reinterpret_cast<float4*>(&Bs[kk][tx*4]);
      float4 bv1 = *reinterpret_cast<float4*>(&Bs[kk][64+tx*4]);
      float a[4] = {av0.x,av0.y,av0.z,av0.w};
      float b[8] = {bv0.x,bv0.y,bv0.z,bv0.w, bv1.x,bv1.y,bv1.z,bv1.w};
      #pragma unroll
      for (int i=0;i<4;i++)
        #pragma unroll
        for (int j=0;j<8;j++)
          acc[i][j] += a[i]*b[j];
    }
    __syncthreads();
  }
  #pragma unroll
  for (int i=0;i<4;i++){
    int row = bm + ty*4 + i;
    if (row < M){
      float* cp = C + (size_t)row*N + bn;
      *reinterpret_cast<float4*>(cp + tx*4)    = make_float4(acc[i][0],acc[i][1],acc[i][2],acc[i][3]);
      *reinterpret_cast<float4*>(cp + 64+tx*4) = make_float4(acc[i][4],acc[i][5],acc[i][6],acc[i][7]);
    }
  }
}

// ============== per-node attention logits s,d = <h, a_src/a_dst> ============
template<int H, int C>
__global__ void sd_kernel(const float* __restrict__ h, const float* __restrict__ asrc,
                          const float* __restrict__ adst, float* __restrict__ s,
                          float* __restrict__ d, int n_nodes){
  int wave = threadIdx.x >> 6, lane = threadIdx.x & 63;
  int n = blockIdx.x*4 + wave;
  if (n >= n_nodes) return;
  const float* hn = h + (size_t)n*H*C;
  #pragma unroll
  for (int hd=0; hd<H; ++hd){
    float ps=0.f, pd=0.f;
    for (int c=lane; c<C; c+=64){
      float v = hn[hd*C+c];
      ps += v*asrc[hd*C+c];
      pd += v*adst[hd*C+c];
    }
    #pragma unroll
    for (int off=32; off; off>>=1){ ps += __shfl_down(ps,off); pd += __shfl_down(pd,off); }
    if (lane==0){ s[n*H+hd]=ps; d[n*H+hd]=pd; }
  }
}

// ================= GAT aggregation: softmax over in-edges ====================
template<int H, int C>
__global__ __launch_bounds__(256) void agg_kernel(
    const float* __restrict__ hbuf, const float* __restrict__ s,
    const float* __restrict__ d, const int* __restrict__ offs,
    const int* __restrict__ csr, const float* __restrict__ bias,
    float* __restrict__ y, int n_nodes){
  constexpr int HC = H*C;
  int n = blockIdx.x;
  int tid = threadIdx.x;
  __shared__ float sdst[H];
  __shared__ float sm[H];
  __shared__ float sl[H];
  __shared__ float wred[4*H];
  __shared__ float sw[64*H];
  __shared__ int ssrc[64];
  if (tid < H) sdst[tid] = d[n*H+tid];
  int start = offs[n];
  int cnt = offs[n+1]-start;
  int cnt1 = cnt+1;                      // + self loop
  __syncthreads();
  float mx[H];
  #pragma unroll
  for (int h=0;h<H;h++) mx[h] = -1e30f;
  for (int i=tid; i<cnt1; i+=256){
    int src = (i==cnt) ? n : csr[start+i];
    #pragma unroll
    for (int h=0;h<H;h++){
      float e = s[src*H+h] + sdst[h];
      e = e>=0.f ? e : NEG_SLOPE*e;
      mx[h] = fmaxf(mx[h], e);
    }
  }
  #pragma unroll
  for (int off=32; off; off>>=1)
    #pragma unroll
    for (int h=0;h<H;h++) mx[h] = fmaxf(mx[h], __shfl_down(mx[h],off));
  int wave = tid>>6, lane = tid&63;
  if (lane==0)
    #pragma unroll
    for (int h=0;h<H;h++) wred[wave*H+h]=mx[h];
  __syncthreads();
  if (tid < H){
    float m = wred[tid];
    for (int w=1;w<4;w++) m = fmaxf(m, wred[w*H+tid]);
    sm[tid]=m;
  }
  __syncthreads();
  float acc = 0.f;
  float lp[H];
  #pragma unroll
  for (int h=0;h<H;h++) lp[h]=0.f;
  int c = tid;
  int head = (tid < HC) ? (c / C) : 0;
  for (int base=0; base<cnt1; base+=64){
    int nchunk = min(64, cnt1-base);
    if (tid < nchunk){
      int i = base+tid;
      int src = (i==cnt) ? n : csr[start+i];
      ssrc[tid]=src;
      #pragma unroll
      for (int h=0;h<H;h++){
        float e = s[src*H+h] + sdst[h];
        e = e>=0.f ? e : NEG_SLOPE*e;
        float w = expf(e - sm[h]);
        sw[tid*H+h]=w;
        lp[h]+=w;
      }
    }
    __syncthreads();
    if (tid < HC){
      for (int j=0;j<nchunk;j++){
        acc += sw[j*H+head] * hbuf[(size_t)ssrc[j]*HC + c];
      }
    }
    __syncthreads();
  }
  if (wave==0){
    #pragma unroll
    for (int off=32; off; off>>=1)
      #pragma unroll
      for (int h=0;h<H;h++) lp[h] += __shfl_down(lp[h],off);
    if (lane==0)
      #pragma unroll
      for (int h=0;h<H;h++) sl[h]=lp[h];
  }
  __syncthreads();
  if (tid < HC){
    float o = acc/(sl[head]+1e-16f) + bias[c];
    y[(size_t)n*HC+c] = o>0.f ? o : expm1f(o);
  }
}

// ======================= Set2Set, fused A/B steps ===========================
// e[i] = <x[i], q[batch[i]]>  (one wave per node)
__global__ __launch_bounds__(256) void e_kernel(
    const float* __restrict__ x, const float* __restrict__ q,
    const int* __restrict__ batch, float* __restrict__ e, int N){
  int tid = threadIdx.x;
  int wave = tid>>6, lane = tid&63;
  int base = blockIdx.x*16;
  #pragma unroll
  for (int j=0;j<4;j++){
    int i = base + wave*4 + j;
    if (i < N){
      int g = batch[i];
      float2 xv = *reinterpret_cast<const float2*>(x + (size_t)i*128 + lane*2);
      float2 qv = *reinterpret_cast<const float2*>(q + (size_t)g*128 + lane*2);
      float p = xv.x*qv.x + xv.y*qv.y;
      #pragma unroll
      for (int off=32; off; off>>=1) p += __shfl_down(p, off);
      if (lane==0) e[i] = p;
    }
  }
}

// STEP s: (s>0) finish step s-1's readout r from e; build qstar=[q_{s-1}, r];
// (s<3) run LSTM -> q_s; (s==3) run scorer instead. One block per graph.
template<int STEP>
__global__ __launch_bounds__(256) void s2s_step_kernel(
    const float* __restrict__ x, const float* __restrict__ e,
    const int* __restrict__ gstart, const int* __restrict__ gend,
    float* __restrict__ hc, float* __restrict__ qbuf,
    const float* __restrict__ Wih, const float* __restrict__ Whh,
    const float* __restrict__ bih, const float* __restrict__ bhh,
    const float* __restrict__ gfeat,
    const float* __restrict__ gW1, const float* __restrict__ gb1,
    const float* __restrict__ gW2, const float* __restrict__ gb2,
    const float* __restrict__ mW1, const float* __restrict__ mb1,
    const float* __restrict__ mW2, const float* __restrict__ mb2,
    float* __restrict__ out, int B){
  int b = blockIdx.x, tid = threadIdx.x;
  __shared__ float qs[256];       // qstar = [q_{s-1}, r_{s-1}]
  __shared__ float red[256];
  __shared__ float lsh[2];

  if (STEP > 0){
    int start = gstart[b], end = gend[b];
    // segment max of e
    float lm = -1e30f;
    for (int i=start+tid; i<end; i+=256) lm = fmaxf(lm, e[i]);
    red[tid]=lm; __syncthreads();
    for (int off=128; off; off>>=1){ if (tid<off) red[tid]=fmaxf(red[tid],red[tid+off]); __syncthreads(); }
    float m = red[0];
    __syncthreads();
    // weighted sums
    int col = tid & 127, half = tid >> 7;
    float rc = 0.f, ls = 0.f;
    for (int i=start+half; i<end; i+=2){
      float w = expf(e[i]-m);
      rc += w * x[(size_t)i*128 + col];
      if (col==0) ls += w;
    }
    if (tid<2) lsh[tid]=0.f;
    __syncthreads();
    red[tid]=rc;
    if (col==0) lsh[half]=ls;
    __syncthreads();
    if (tid < 128){
      float r = (red[tid]+red[tid+128]) / (lsh[0]+lsh[1]+1e-16f);
      qs[tid]     = qbuf[b*128+tid];
      qs[128+tid] = r;
    }
    __syncthreads();
  }

  if (STEP < 3){
    // LSTM: gates = qstar @ Wih.T + bih + h @ Whh.T + bhh
    __shared__ float hs[128], gsh[512];
    if (STEP > 0){ if (tid<128) hs[tid] = hc[(size_t)b*128+tid]; }
    __syncthreads();
    #pragma unroll
    for (int p=0;p<2;p++){
      int j = tid + p*256;
      float a = bih[j] + bhh[j];
      if (STEP > 0){
        const float* wi = Wih + (size_t)j*256;
        for (int k=0;k<256;k+=4)
          a += qs[k]*wi[k] + qs[k+1]*wi[k+1] + qs[k+2]*wi[k+2] + qs[k+3]*wi[k+3];
        const float* wh = Whh + (size_t)j*128;
        for (int k=0;k<128;k+=4)
          a += hs[k]*wh[k] + hs[k+1]*wh[k+1] + hs[k+2]*wh[k+2] + hs[k+3]*wh[k+3];
      }
      gsh[j] = a;
    }
    __syncthreads();
    if (tid < 128){
      float cprev = (STEP==0) ? 0.f : hc[(size_t)(B+b)*128+tid];
      float ig = sigmoidf(gsh[tid]);
      float fg = sigmoidf(gsh[128+tid]);
      float gg = tanhf(gsh[256+tid]);
      float og = sigmoidf(gsh[384+tid]);
      float c2 = fg*cprev + ig*gg;
      float h2 = og*tanhf(c2);
      hc[(size_t)b*128+tid] = h2;
      hc[(size_t)(B+b)*128+tid] = c2;
      qbuf[b*128+tid] = h2;
    }
  } else {
    // scorer: z = [qstar, gf-MLP]; out = relu(z@mW1+mb1)@mW2+mb2
    __shared__ float z[288], gf1[64], hid[128];
    z[tid] = qs[tid];
    if (tid < 64){
      float a = gb1[tid];
      for (int k=0;k<9;k++) a += gfeat[b*9+k]*gW1[k*64+tid];
      gf1[tid] = a>0.f ? a : 0.f;
    }
    __syncthreads();
    if (tid < 32){
      float a = gb2[tid];
      for (int k=0;k<64;k++) a += gf1[k]*gW2[k*32+tid];
      z[256+tid] = a;
    }
    __syncthreads();
    if (tid < 128){
      float a = mb1[tid];
      for (int k=0;k<288;k++) a += z[k]*mW1[(size_t)k*128+tid];
      hid[tid] = a>0.f ? a : 0.f;
    }
    __syncthreads();
    if (tid < 4){
      float a = mb2[tid];
      for (int k=0;k<128;k++) a += hid[k]*mW2[k*4+tid];
      out[b*4+tid] = a;
    }
  }
}

// ================================ launch ====================================
extern "C" void kernel_launch(void* const* d_in, const int* in_sizes, int n_in,
                              void* d_out, int out_size, void* d_ws, size_t ws_size,
                              hipStream_t stream) {
  const float* x     = (const float*)d_in[0];
  const int*   ei    = (const int*)d_in[1];
  const int*   batch = (const int*)d_in[2];
  const float* gfeat = (const float*)d_in[3];
  const float* W1    = (const float*)d_in[4];
  const float* as1   = (const float*)d_in[5];
  const float* ad1   = (const float*)d_in[6];
  const float* b1    = (const float*)d_in[7];
  const float* W2    = (const float*)d_in[8];
  const float* as2   = (const float*)d_in[9];
  const float* ad2   = (const float*)d_in[10];
  const float* b2    = (const float*)d_in[11];
  const float* W3    = (const float*)d_in[12];
  const float* as3   = (const float*)d_in[13];
  const float* ad3   = (const float*)d_in[14];
  const float* b3    = (const float*)d_in[15];
  const float* Wih   = (const float*)d_in[16];
  const float* Whh   = (const float*)d_in[17];
  const float* bih   = (const float*)d_in[18];
  const float* bhh   = (const float*)d_in[19];
  const float* gW1   = (const float*)d_in[20];
  const float* gb1   = (const float*)d_in[21];
  const float* gW2   = (const float*)d_in[22];
  const float* gb2   = (const float*)d_in[23];
  const float* mW1   = (const float*)d_in[24];
  const float* mb1   = (const float*)d_in[25];
  const float* mW2   = (const float*)d_in[26];
  const float* mb2   = (const float*)d_in[27];

  const int N = in_sizes[0]/128;   // 20000
  const int E = in_sizes[1]/2;     // 320000
  const int B = in_sizes[3]/9;     // 64

  char* ws = (char*)d_ws;
  size_t off = 0;
  auto alloc = [&](size_t bytes)->char*{
    char* p = ws + off;
    off += (bytes + 255) & ~(size_t)255;
    return p;
  };
  float* hbuf   = (float*)alloc((size_t)N*256*4);
  float* ybuf1  = (float*)alloc((size_t)N*256*4);
  float* ybuf2  = (float*)alloc((size_t)N*256*4);
  float* sbuf   = (float*)alloc((size_t)N*4*4);
  float* dbuf   = (float*)alloc((size_t)N*4*4);
  float* e_ws   = (float*)alloc((size_t)N*4);
  int*   counts = (int*)alloc((size_t)N*4);
  int*   offs   = (int*)alloc((size_t)(N+1)*4);
  int*   cursor = (int*)alloc((size_t)N*4);
  int*   csr    = (int*)alloc((size_t)E*4);
  int*   gstart = (int*)alloc((size_t)B*4);
  int*   gend   = (int*)alloc((size_t)B*4);
  float* hcbuf  = (float*)alloc((size_t)2*B*128*4);
  float* qbuf   = (float*)alloc((size_t)B*128*4);

  int gridEN = (max(E,N)+255)/256;
  init_kernel<<<(max(N,B)+255)/256, 256, 0, stream>>>(counts, gstart, gend, N, B);
  build_kernel<<<gridEN, 256, 0, stream>>>(ei, batch, counts, gstart, gend, E, N);
  scan_kernel<<<1, 1024, 0, stream>>>(counts, offs, cursor, N);
  fill_kernel<<<(E+255)/256, 256, 0, stream>>>(ei, cursor, csr, E);

  int gm = (N+63)/64;
  // ---- layer 1: x[N,128] -> h[N,256] -> y1
  gemm64x128<<<dim3(gm,2), 256, 0, stream>>>(x, W1, hbuf, N, 128, 256);
  sd_kernel<4,64><<<(N+3)/4, 256, 0, stream>>>(hbuf, as1, ad1, sbuf, dbuf, N);
  agg_kernel<4,64><<<N, 256, 0, stream>>>(hbuf, sbuf, dbuf, offs, csr, b1, ybuf1, N);
  // ---- layer 2: y1[N,256] -> h[N,256] -> y2
  gemm64x128<<<dim3(gm,2), 256, 0, stream>>>(ybuf1, W2, hbuf, N, 256, 256);
  sd_kernel<4,64><<<(N+3)/4, 256, 0, stream>>>(hbuf, as2, ad2, sbuf, dbuf, N);
  agg_kernel<4,64><<<N, 256, 0, stream>>>(hbuf, sbuf, dbuf, offs, csr, b2, ybuf2, N);
  // ---- layer 3: y2[N,256] -> h[N,128] -> y1 (reuse)
  gemm64x128<<<dim3(gm,1), 256, 0, stream>>>(ybuf2, W3, hbuf, N, 256, 128);
  sd_kernel<1,128><<<(N+3)/4, 256, 0, stream>>>(hbuf, as3, ad3, sbuf, dbuf, N);
  agg_kernel<1,128><<<N, 256, 0, stream>>>(hbuf, sbuf, dbuf, offs, csr, b3, ybuf1, N);
  // ---- set2set (fused steps) + scorer ----
  int ge = (N+15)/16;
  s2s_step_kernel<0><<<B, 256, 0, stream>>>(ybuf1, e_ws, gstart, gend, hcbuf, qbuf,
      Wih, Whh, bih, bhh, gfeat, gW1, gb1, gW2, gb2, mW1, mb1, mW2, mb2, (float*)d_out, B);
  e_kernel<<<ge, 256, 0, stream>>>(ybuf1, qbuf, batch, e_ws, N);
  s2s_step_kernel<1><<<B, 256, 0, stream>>>(ybuf1, e_ws, gstart, gend, hcbuf, qbuf,
      Wih, Whh, bih, bhh, gfeat, gW1, gb1, gW2, gb2, mW1, mb1, mW2, mb2, (float*)d_out, B);
  e_kernel<<<ge, 256, 0, stream>>>(ybuf1, qbuf, batch, e_ws, N);
  s2s_step_kernel<2><<<B, 256, 0, stream>>>(ybuf1, e_ws, gstart, gend, hcbuf, qbuf,
      Wih, Whh, bih, bhh, gfeat, gW1, gb1, gW2, gb2, mW1, mb1, mW2, mb2, (float*)d_out, B);
  e_kernel<<<ge, 256, 0, stream>>>(ybuf1, qbuf, batch, e_ws, N);
  s2s_step_kernel<3><<<B, 256, 0, stream>>>(ybuf1, e_ws, gstart, gend, hcbuf, qbuf,
      Wih, Whh, bih, bhh, gfeat, gW1, gb1, gW2, gb2, mW1, mb1, mW2, mb2, (float*)d_out, B);
}

// Round 4
// 614.946 us; speedup vs baseline: 1.3322x; 1.0456x over previous
//
#include <hip/hip_runtime.h>
#include <hip/hip_bf16.h>
#include <math.h>

#define NEG_SLOPE 0.2f

__device__ __forceinline__ float sigmoidf(float x){ return 1.f/(1.f+expf(-x)); }
__device__ __forceinline__ unsigned fenc(float f){
  unsigned u = __float_as_uint(f);
  return (u & 0x80000000u) ? ~u : (u | 0x80000000u);
}
__device__ __forceinline__ float fdec(unsigned u){
  return (u & 0x80000000u) ? __uint_as_float(u & 0x7fffffffu) : __uint_as_float(~u);
}

// ============================ init + CSR build ==============================
// Zeroes counts, graph bounds, and the per-step set2set accumulators
// (rsum/lsum/menc) every call (harness re-poisons d_ws to 0xAA).
__global__ void init_kernel(int* counts, int* gstart, int* gend,
                            float* rsum, float* lsum, unsigned* menc,
                            int n, int b){
  int i = blockIdx.x*blockDim.x + threadIdx.x;
  if (i < n) counts[i] = 0;
  if (i < b){ gstart[i] = 0; gend[i] = 0; }
  if (i < 3*b*128) rsum[i] = 0.f;
  if (i < 3*b){ lsum[i] = 0.f; menc[i] = 0u; }
}

// counts via atomics (16-way mean contention); graph bounds via sorted-batch
// boundary detection (NO atomics - 64-address atomicMin/Max chains were 122us).
__global__ void build_kernel(const int* __restrict__ ei, const int* __restrict__ batch,
                             int* counts, int* gstart, int* gend, int E, int n){
  int i = blockIdx.x*blockDim.x + threadIdx.x;
  if (i < E) atomicAdd(&counts[ei[E+i]], 1);
  if (i < n){
    int b = batch[i];
    if (i == 0 || batch[i-1] != b) gstart[b] = i;
    if (i == n-1 || batch[i+1] != b) gend[b] = i+1;
  }
}

__global__ void scan_kernel(const int* __restrict__ counts, int* offs, int* cursor, int n){
  const int T = 1024;
  int tid = threadIdx.x;
  int chunk = (n + T - 1)/T;
  int base = tid*chunk;
  int local = 0;
  for (int i=0;i<chunk;i++){ int idx=base+i; if (idx<n) local += counts[idx]; }
  __shared__ int ss[T];
  ss[tid]=local; __syncthreads();
  for (int off=1; off<T; off<<=1){
    int v = (tid>=off)? ss[tid-off] : 0;
    __syncthreads();
    ss[tid]+=v;
    __syncthreads();
  }
  int run = ss[tid]-local;  // exclusive prefix
  for (int i=0;i<chunk;i++){
    int idx=base+i;
    if (idx<n){ offs[idx]=run; cursor[idx]=run; run += counts[idx]; }
  }
  if (tid==T-1) offs[n]=run;
}

__global__ void fill_kernel(const int* __restrict__ ei, int* cursor, int* csr, int E){
  int i = blockIdx.x*blockDim.x + threadIdx.x;
  if (i<E){
    int dst = ei[E+i];
    int pos = atomicAdd(&cursor[dst],1);
    csr[pos] = ei[i];
  }
}

// ============================ fp32 tiled GEMM ===============================
// C[M,N] = A[M,K] @ B[K,N], row-major. BM=64, BN=128, BK=16, 256 threads,
// 4x8 micro-tile with split-4 cols -> float4 LDS reads, 2-way aliasing (free).
__global__ __launch_bounds__(256) void gemm64x128(const float* __restrict__ A,
                                                  const float* __restrict__ B,
                                                  float* __restrict__ C,
                                                  int M, int K, int N){
  __shared__ float As[16][64];
  __shared__ float Bs[16][128];
  int tid = threadIdx.x;
  int bm = blockIdx.x*64, bn = blockIdx.y*128;
  int ar = tid>>2, ak=(tid&3)*4;        // A: 64 rows x 16 k, float4/thread
  int br = tid>>4, bc=(tid&15)*8;       // B: 16 rows x 128 cols, 8 floats/thread
  int ty = tid>>4, tx = tid&15;
  float acc[4][8] = {};
  for (int k0=0; k0<K; k0+=16){
    float4 av = make_float4(0,0,0,0);
    if (bm+ar < M) av = *reinterpret_cast<const float4*>(A + (size_t)(bm+ar)*K + k0 + ak);
    const float* bp = B + (size_t)(k0+br)*N + bn + bc;
    float4 b0 = *reinterpret_cast<const float4*>(bp);
    float4 b1 = *reinterpret_cast<const float4*>(bp+4);
    As[ak+0][ar]=av.x; As[ak+1][ar]=av.y; As[ak+2][ar]=av.z; As[ak+3][ar]=av.w;
    *reinterpret_cast<float4*>(&Bs[br][bc])   = b0;
    *reinterpret_cast<float4*>(&Bs[br][bc+4]) = b1;
    __syncthreads();
    #pragma unroll
    for (int kk=0; kk<16; kk++){
      float4 av0 = *reinterpret_cast<float4*>(&As[kk][ty*4]);
      float4 bv0 = *reinterpret_cast<float4*>(&Bs[kk][tx*4]);
      float4 bv1 = *reinterpret_cast<float4*>(&Bs[kk][64+tx*4]);
      float a[4] = {av0.x,av0.y,av0.z,av0.w};
      float b[8] = {bv0.x,bv0.y,bv0.z,bv0.w, bv1.x,bv1.y,bv1.z,bv1.w};
      #pragma unroll
      for (int i=0;i<4;i++)
        #pragma unroll
        for (int j=0;j<8;j++)
          acc[i][j] += a[i]*b[j];
    }
    __syncthreads();
  }
  #pragma unroll
  for (int i=0;i<4;i++){
    int row = bm + ty*4 + i;
    if (row < M){
      float* cp = C + (size_t)row*N + bn;
      *reinterpret_cast<float4*>(cp + tx*4)    = make_float4(acc[i][0],acc[i][1],acc[i][2],acc[i][3]);
      *reinterpret_cast<float4*>(cp + 64+tx*4) = make_float4(acc[i][4],acc[i][5],acc[i][6],acc[i][7]);
    }
  }
}

// ============== per-node attention logits s,d = <h, a_src/a_dst> ============
template<int H, int C>
__global__ void sd_kernel(const float* __restrict__ h, const float* __restrict__ asrc,
                          const float* __restrict__ adst, float* __restrict__ s,
                          float* __restrict__ d, int n_nodes){
  int wave = threadIdx.x >> 6, lane = threadIdx.x & 63;
  int n = blockIdx.x*4 + wave;
  if (n >= n_nodes) return;
  const float* hn = h + (size_t)n*H*C;
  #pragma unroll
  for (int hd=0; hd<H; ++hd){
    float ps=0.f, pd=0.f;
    for (int c=lane; c<C; c+=64){
      float v = hn[hd*C+c];
      ps += v*asrc[hd*C+c];
      pd += v*adst[hd*C+c];
    }
    #pragma unroll
    for (int off=32; off; off>>=1){ ps += __shfl_down(ps,off); pd += __shfl_down(pd,off); }
    if (lane==0){ s[n*H+hd]=ps; d[n*H+hd]=pd; }
  }
}

// ================= GAT aggregation: softmax over in-edges ====================
template<int H, int C>
__global__ __launch_bounds__(256) void agg_kernel(
    const float* __restrict__ hbuf, const float* __restrict__ s,
    const float* __restrict__ d, const int* __restrict__ offs,
    const int* __restrict__ csr, const float* __restrict__ bias,
    float* __restrict__ y, int n_nodes){
  constexpr int HC = H*C;
  int n = blockIdx.x;
  int tid = threadIdx.x;
  __shared__ float sdst[H];
  __shared__ float sm[H];
  __shared__ float sl[H];
  __shared__ float wred[4*H];
  __shared__ float sw[64*H];
  __shared__ int ssrc[64];
  if (tid < H) sdst[tid] = d[n*H+tid];
  int start = offs[n];
  int cnt = offs[n+1]-start;
  int cnt1 = cnt+1;                      // + self loop
  __syncthreads();
  float mx[H];
  #pragma unroll
  for (int h=0;h<H;h++) mx[h] = -1e30f;
  for (int i=tid; i<cnt1; i+=256){
    int src = (i==cnt) ? n : csr[start+i];
    #pragma unroll
    for (int h=0;h<H;h++){
      float e = s[src*H+h] + sdst[h];
      e = e>=0.f ? e : NEG_SLOPE*e;
      mx[h] = fmaxf(mx[h], e);
    }
  }
  #pragma unroll
  for (int off=32; off; off>>=1)
    #pragma unroll
    for (int h=0;h<H;h++) mx[h] = fmaxf(mx[h], __shfl_down(mx[h],off));
  int wave = tid>>6, lane = tid&63;
  if (lane==0)
    #pragma unroll
    for (int h=0;h<H;h++) wred[wave*H+h]=mx[h];
  __syncthreads();
  if (tid < H){
    float m = wred[tid];
    for (int w=1;w<4;w++) m = fmaxf(m, wred[w*H+tid]);
    sm[tid]=m;
  }
  __syncthreads();
  float acc = 0.f;
  float lp[H];
  #pragma unroll
  for (int h=0;h<H;h++) lp[h]=0.f;
  int c = tid;
  int head = (tid < HC) ? (c / C) : 0;
  for (int base=0; base<cnt1; base+=64){
    int nchunk = min(64, cnt1-base);
    if (tid < nchunk){
      int i = base+tid;
      int src = (i==cnt) ? n : csr[start+i];
      ssrc[tid]=src;
      #pragma unroll
      for (int h=0;h<H;h++){
        float e = s[src*H+h] + sdst[h];
        e = e>=0.f ? e : NEG_SLOPE*e;
        float w = expf(e - sm[h]);
        sw[tid*H+h]=w;
        lp[h]+=w;
      }
    }
    __syncthreads();
    if (tid < HC){
      for (int j=0;j<nchunk;j++){
        acc += sw[j*H+head] * hbuf[(size_t)ssrc[j]*HC + c];
      }
    }
    __syncthreads();
  }
  if (wave==0){
    #pragma unroll
    for (int off=32; off; off>>=1)
      #pragma unroll
      for (int h=0;h<H;h++) lp[h] += __shfl_down(lp[h],off);
    if (lane==0)
      #pragma unroll
      for (int h=0;h<H;h++) sl[h]=lp[h];
  }
  __syncthreads();
  if (tid < HC){
    float o = acc/(sl[head]+1e-16f) + bias[c];
    y[(size_t)n*HC+c] = o>0.f ? o : expm1f(o);
  }
}

// ======================= Set2Set, grid-parallel =============================
// e[i] = <x[i], q[batch[i]]> + per-graph running max (block-local LDS max,
// then <=#graphs-in-block global encoded atomicMax).
__global__ __launch_bounds__(256) void e_kernel(
    const float* __restrict__ x, const float* __restrict__ q,
    const int* __restrict__ batch, float* __restrict__ e,
    unsigned* __restrict__ menc, int N){
  int tid = threadIdx.x;
  int wave = tid>>6, lane = tid&63;
  int base = blockIdx.x*16;
  __shared__ unsigned lm[64];
  if (tid < 64) lm[tid] = 0u;
  __syncthreads();
  #pragma unroll
  for (int j=0;j<4;j++){
    int i = base + wave*4 + j;
    if (i < N){
      int g = batch[i];
      float2 xv = *reinterpret_cast<const float2*>(x + (size_t)i*128 + lane*2);
      float2 qv = *reinterpret_cast<const float2*>(q + (size_t)g*128 + lane*2);
      float p = xv.x*qv.x + xv.y*qv.y;
      #pragma unroll
      for (int off=32; off; off>>=1) p += __shfl_down(p, off);
      if (lane==0){
        e[i] = p;
        atomicMax(&lm[g], fenc(p));
      }
    }
  }
  __syncthreads();
  if (tid < 64 && lm[tid]) atomicMax(&menc[tid], lm[tid]);
}

// Grid-parallel weighted readout: rsum[g][col] += sum_i exp(e_i - m_g) x[i,col],
// lsum[g] += sum_i exp(e_i - m_g). 128 threads/block, 32 contiguous (sorted)
// nodes/block; register-accumulate per graph run, flush on boundary.
__global__ __launch_bounds__(128) void racc_kernel(
    const float* __restrict__ x, const float* __restrict__ e,
    const int* __restrict__ batch, const unsigned* __restrict__ menc,
    float* __restrict__ rsum, float* __restrict__ lsum, int N){
  int col = threadIdx.x;
  int c0 = blockIdx.x*32;
  int endi = min(c0+32, N);
  if (c0 >= N) return;
  int curg = batch[c0];
  float m = fdec(menc[curg]);
  float acc = 0.f, lacc = 0.f;
  for (int i=c0; i<endi; ++i){
    int g = batch[i];
    if (g != curg){
      atomicAdd(&rsum[curg*128+col], acc);
      if (col==0) atomicAdd(&lsum[curg], lacc);
      acc = 0.f; lacc = 0.f; curg = g; m = fdec(menc[g]);
    }
    float w = expf(e[i]-m);
    acc += w * x[(size_t)i*128+col];
    lacc += w;
  }
  atomicAdd(&rsum[curg*128+col], acc);
  if (col==0) atomicAdd(&lsum[curg], lacc);
}

// STEP s: (s>0) r = rsum/lsum from step s-1; qstar=[q_{s-1}, r];
// (s<3) LSTM -> q_s; (s==3) scorer. One block per graph (tiny work).
template<int STEP>
__global__ __launch_bounds__(256) void s2s_step_kernel(
    const float* __restrict__ rsum, const float* __restrict__ lsum,
    float* __restrict__ hc, float* __restrict__ qbuf,
    const float* __restrict__ Wih, const float* __restrict__ Whh,
    const float* __restrict__ bih, const float* __restrict__ bhh,
    const float* __restrict__ gfeat,
    const float* __restrict__ gW1, const float* __restrict__ gb1,
    const float* __restrict__ gW2, const float* __restrict__ gb2,
    const float* __restrict__ mW1, const float* __restrict__ mb1,
    const float* __restrict__ mW2, const float* __restrict__ mb2,
    float* __restrict__ out, int B){
  int b = blockIdx.x, tid = threadIdx.x;
  __shared__ float qs[256];       // qstar = [q_{s-1}, r_{s-1}]

  if (STEP > 0){
    if (tid < 128){
      const float* rs = rsum + (size_t)(STEP-1)*B*128 + (size_t)b*128;
      float ls = lsum[(STEP-1)*B + b];
      qs[tid]     = qbuf[b*128+tid];
      qs[128+tid] = rs[tid] / (ls + 1e-16f);
    }
    __syncthreads();
  }

  if (STEP < 3){
    __shared__ float hs[128], gsh[512];
    if (STEP > 0){ if (tid<128) hs[tid] = hc[(size_t)b*128+tid]; }
    __syncthreads();
    #pragma unroll
    for (int p=0;p<2;p++){
      int j = tid + p*256;
      float a = bih[j] + bhh[j];
      if (STEP > 0){
        const float* wi = Wih + (size_t)j*256;
        for (int k=0;k<256;k+=4)
          a += qs[k]*wi[k] + qs[k+1]*wi[k+1] + qs[k+2]*wi[k+2] + qs[k+3]*wi[k+3];
        const float* wh = Whh + (size_t)j*128;
        for (int k=0;k<128;k+=4)
          a += hs[k]*wh[k] + hs[k+1]*wh[k+1] + hs[k+2]*wh[k+2] + hs[k+3]*wh[k+3];
      }
      gsh[j] = a;
    }
    __syncthreads();
    if (tid < 128){
      float cprev = (STEP==0) ? 0.f : hc[(size_t)(B+b)*128+tid];
      float ig = sigmoidf(gsh[tid]);
      float fg = sigmoidf(gsh[128+tid]);
      float gg = tanhf(gsh[256+tid]);
      float og = sigmoidf(gsh[384+tid]);
      float c2 = fg*cprev + ig*gg;
      float h2 = og*tanhf(c2);
      hc[(size_t)b*128+tid] = h2;
      hc[(size_t)(B+b)*128+tid] = c2;
      qbuf[b*128+tid] = h2;
    }
  } else {
    __shared__ float z[288], gf1[64], hid[128];
    z[tid] = qs[tid];
    if (tid < 64){
      float a = gb1[tid];
      for (int k=0;k<9;k++) a += gfeat[b*9+k]*gW1[k*64+tid];
      gf1[tid] = a>0.f ? a : 0.f;
    }
    __syncthreads();
    if (tid < 32){
      float a = gb2[tid];
      for (int k=0;k<64;k++) a += gf1[k]*gW2[k*32+tid];
      z[256+tid] = a;
    }
    __syncthreads();
    if (tid < 128){
      float a = mb1[tid];
      for (int k=0;k<288;k++) a += z[k]*mW1[(size_t)k*128+tid];
      hid[tid] = a>0.f ? a : 0.f;
    }
    __syncthreads();
    if (tid < 4){
      float a = mb2[tid];
      for (int k=0;k<128;k++) a += hid[k]*mW2[k*4+tid];
      out[b*4+tid] = a;
    }
  }
}

// ================================ launch ====================================
extern "C" void kernel_launch(void* const* d_in, const int* in_sizes, int n_in,
                              void* d_out, int out_size, void* d_ws, size_t ws_size,
                              hipStream_t stream) {
  const float* x     = (const float*)d_in[0];
  const int*   ei    = (const int*)d_in[1];
  const int*   batch = (const int*)d_in[2];
  const float* gfeat = (const float*)d_in[3];
  const float* W1    = (const float*)d_in[4];
  const float* as1   = (const float*)d_in[5];
  const float* ad1   = (const float*)d_in[6];
  const float* b1    = (const float*)d_in[7];
  const float* W2    = (const float*)d_in[8];
  const float* as2   = (const float*)d_in[9];
  const float* ad2   = (const float*)d_in[10];
  const float* b2    = (const float*)d_in[11];
  const float* W3    = (const float*)d_in[12];
  const float* as3   = (const float*)d_in[13];
  const float* ad3   = (const float*)d_in[14];
  const float* b3    = (const float*)d_in[15];
  const float* Wih   = (const float*)d_in[16];
  const float* Whh   = (const float*)d_in[17];
  const float* bih   = (const float*)d_in[18];
  const float* bhh   = (const float*)d_in[19];
  const float* gW1   = (const float*)d_in[20];
  const float* gb1   = (const float*)d_in[21];
  const float* gW2   = (const float*)d_in[22];
  const float* gb2   = (const float*)d_in[23];
  const float* mW1   = (const float*)d_in[24];
  const float* mb1   = (const float*)d_in[25];
  const float* mW2   = (const float*)d_in[26];
  const float* mb2   = (const float*)d_in[27];

  const int N = in_sizes[0]/128;   // 20000
  const int E = in_sizes[1]/2;     // 320000
  const int B = in_sizes[3]/9;     // 64

  char* ws = (char*)d_ws;
  size_t off = 0;
  auto alloc = [&](size_t bytes)->char*{
    char* p = ws + off;
    off += (bytes + 255) & ~(size_t)255;
    return p;
  };
  float* hbuf   = (float*)alloc((size_t)N*256*4);
  float* ybuf1  = (float*)alloc((size_t)N*256*4);
  float* ybuf2  = (float*)alloc((size_t)N*256*4);
  float* sbuf   = (float*)alloc((size_t)N*4*4);
  float* dbuf   = (float*)alloc((size_t)N*4*4);
  float* e_ws   = (float*)alloc((size_t)N*4);
  int*   counts = (int*)alloc((size_t)N*4);
  int*   offs   = (int*)alloc((size_t)(N+1)*4);
  int*   cursor = (int*)alloc((size_t)N*4);
  int*   csr    = (int*)alloc((size_t)E*4);
  int*   gstart = (int*)alloc((size_t)B*4);
  int*   gend   = (int*)alloc((size_t)B*4);
  float* hcbuf  = (float*)alloc((size_t)2*B*128*4);
  float* qbuf   = (float*)alloc((size_t)B*128*4);
  float* rsum   = (float*)alloc((size_t)3*B*128*4);
  float* lsum   = (float*)alloc((size_t)3*B*4);
  unsigned* menc= (unsigned*)alloc((size_t)3*B*4);

  int nInit = max(N, 3*B*128);
  init_kernel<<<(nInit+255)/256, 256, 0, stream>>>(counts, gstart, gend,
                                                   rsum, lsum, menc, N, B);
  int gridEN = (max(E,N)+255)/256;
  build_kernel<<<gridEN, 256, 0, stream>>>(ei, batch, counts, gstart, gend, E, N);
  scan_kernel<<<1, 1024, 0, stream>>>(counts, offs, cursor, N);
  fill_kernel<<<(E+255)/256, 256, 0, stream>>>(ei, cursor, csr, E);

  int gm = (N+63)/64;
  // ---- layer 1: x[N,128] -> h[N,256] -> y1
  gemm64x128<<<dim3(gm,2), 256, 0, stream>>>(x, W1, hbuf, N, 128, 256);
  sd_kernel<4,64><<<(N+3)/4, 256, 0, stream>>>(hbuf, as1, ad1, sbuf, dbuf, N);
  agg_kernel<4,64><<<N, 256, 0, stream>>>(hbuf, sbuf, dbuf, offs, csr, b1, ybuf1, N);
  // ---- layer 2: y1[N,256] -> h[N,256] -> y2
  gemm64x128<<<dim3(gm,2), 256, 0, stream>>>(ybuf1, W2, hbuf, N, 256, 256);
  sd_kernel<4,64><<<(N+3)/4, 256, 0, stream>>>(hbuf, as2, ad2, sbuf, dbuf, N);
  agg_kernel<4,64><<<N, 256, 0, stream>>>(hbuf, sbuf, dbuf, offs, csr, b2, ybuf2, N);
  // ---- layer 3: y2[N,256] -> h[N,128] -> y1 (reuse)
  gemm64x128<<<dim3(gm,1), 256, 0, stream>>>(ybuf2, W3, hbuf, N, 256, 128);
  sd_kernel<1,128><<<(N+3)/4, 256, 0, stream>>>(hbuf, as3, ad3, sbuf, dbuf, N);
  agg_kernel<1,128><<<N, 256, 0, stream>>>(hbuf, sbuf, dbuf, offs, csr, b3, ybuf1, N);

  // ---- set2set (grid-parallel readout) + scorer ----
  int ge = (N+15)/16;
  int gr = (N+31)/32;
  s2s_step_kernel<0><<<B, 256, 0, stream>>>(rsum, lsum, hcbuf, qbuf,
      Wih, Whh, bih, bhh, gfeat, gW1, gb1, gW2, gb2, mW1, mb1, mW2, mb2, (float*)d_out, B);
  e_kernel<<<ge, 256, 0, stream>>>(ybuf1, qbuf, batch, e_ws, menc + 0*B, N);
  racc_kernel<<<gr, 128, 0, stream>>>(ybuf1, e_ws, batch, menc + 0*B, rsum + 0*(size_t)B*128, lsum + 0*B, N);
  s2s_step_kernel<1><<<B, 256, 0, stream>>>(rsum, lsum, hcbuf, qbuf,
      Wih, Whh, bih, bhh, gfeat, gW1, gb1, gW2, gb2, mW1, mb1, mW2, mb2, (float*)d_out, B);
  e_kernel<<<ge, 256, 0, stream>>>(ybuf1, qbuf, batch, e_ws, menc + 1*B, N);
  racc_kernel<<<gr, 128, 0, stream>>>(ybuf1, e_ws, batch, menc + 1*B, rsum + 1*(size_t)B*128, lsum + 1*B, N);
  s2s_step_kernel<2><<<B, 256, 0, stream>>>(rsum, lsum, hcbuf, qbuf,
      Wih, Whh, bih, bhh, gfeat, gW1, gb1, gW2, gb2, mW1, mb1, mW2, mb2, (float*)d_out, B);
  e_kernel<<<ge, 256, 0, stream>>>(ybuf1, qbuf, batch, e_ws, menc + 2*B, N);
  racc_kernel<<<gr, 128, 0, stream>>>(ybuf1, e_ws, batch, menc + 2*B, rsum + 2*(size_t)B*128, lsum + 2*B, N);
  s2s_step_kernel<3><<<B, 256, 0, stream>>>(rsum, lsum, hcbuf, qbuf,
      Wih, Whh, bih, bhh, gfeat, gW1, gb1, gW2, gb2, mW1, mb1, mW2, mb2, (float*)d_out, B);
}

// Round 5
// 612.709 us; speedup vs baseline: 1.3371x; 1.0037x over previous
//
#include <hip/hip_runtime.h>
#include <hip/hip_bf16.h>
#include <math.h>

#define NEG_SLOPE 0.2f

__device__ __forceinline__ float sigmoidf(float x){ return 1.f/(1.f+expf(-x)); }
__device__ __forceinline__ unsigned fenc(float f){
  unsigned u = __float_as_uint(f);
  return (u & 0x80000000u) ? ~u : (u | 0x80000000u);
}
__device__ __forceinline__ float fdec(unsigned u){
  return (u & 0x80000000u) ? __uint_as_float(u & 0x7fffffffu) : __uint_as_float(~u);
}

// ============================ init + CSR build ==============================
__global__ void init_kernel(int* counts, int* gstart, int* gend,
                            float* rsum, float* lsum, unsigned* menc,
                            int n, int b){
  int i = blockIdx.x*blockDim.x + threadIdx.x;
  if (i < n) counts[i] = 0;
  if (i < b){ gstart[i] = 0; gend[i] = 0; }
  if (i < 3*b*128) rsum[i] = 0.f;
  if (i < 3*b){ lsum[i] = 0.f; menc[i] = 0u; }
}

// counts via atomics (16-way mean contention); graph bounds via sorted-batch
// boundary detection (NO atomics - 64-address atomicMin/Max chains were 122us).
__global__ void build_kernel(const int* __restrict__ ei, const int* __restrict__ batch,
                             int* counts, int* gstart, int* gend, int E, int n){
  int i = blockIdx.x*blockDim.x + threadIdx.x;
  if (i < E) atomicAdd(&counts[ei[E+i]], 1);
  if (i < n){
    int b = batch[i];
    if (i == 0 || batch[i-1] != b) gstart[b] = i;
    if (i == n-1 || batch[i+1] != b) gend[b] = i+1;
  }
}

__global__ void scan_kernel(const int* __restrict__ counts, int* offs, int* cursor, int n){
  const int T = 1024;
  int tid = threadIdx.x;
  int chunk = (n + T - 1)/T;
  int base = tid*chunk;
  int local = 0;
  for (int i=0;i<chunk;i++){ int idx=base+i; if (idx<n) local += counts[idx]; }
  __shared__ int ss[T];
  ss[tid]=local; __syncthreads();
  for (int off=1; off<T; off<<=1){
    int v = (tid>=off)? ss[tid-off] : 0;
    __syncthreads();
    ss[tid]+=v;
    __syncthreads();
  }
  int run = ss[tid]-local;  // exclusive prefix
  for (int i=0;i<chunk;i++){
    int idx=base+i;
    if (idx<n){ offs[idx]=run; cursor[idx]=run; run += counts[idx]; }
  }
  if (tid==T-1) offs[n]=run;
}

__global__ void fill_kernel(const int* __restrict__ ei, int* cursor, int* csr, int E){
  int i = blockIdx.x*blockDim.x + threadIdx.x;
  if (i<E){
    int dst = ei[E+i];
    int pos = atomicAdd(&cursor[dst],1);
    csr[pos] = ei[i];
  }
}

// ============================ fp32 tiled GEMM ===============================
__global__ __launch_bounds__(256) void gemm64x128(const float* __restrict__ A,
                                                  const float* __restrict__ B,
                                                  float* __restrict__ C,
                                                  int M, int K, int N){
  __shared__ float As[16][64];
  __shared__ float Bs[16][128];
  int tid = threadIdx.x;
  int bm = blockIdx.x*64, bn = blockIdx.y*128;
  int ar = tid>>2, ak=(tid&3)*4;
  int br = tid>>4, bc=(tid&15)*8;
  int ty = tid>>4, tx = tid&15;
  float acc[4][8] = {};
  for (int k0=0; k0<K; k0+=16){
    float4 av = make_float4(0,0,0,0);
    if (bm+ar < M) av = *reinterpret_cast<const float4*>(A + (size_t)(bm+ar)*K + k0 + ak);
    const float* bp = B + (size_t)(k0+br)*N + bn + bc;
    float4 b0 = *reinterpret_cast<const float4*>(bp);
    float4 b1 = *reinterpret_cast<const float4*>(bp+4);
    As[ak+0][ar]=av.x; As[ak+1][ar]=av.y; As[ak+2][ar]=av.z; As[ak+3][ar]=av.w;
    *reinterpret_cast<float4*>(&Bs[br][bc])   = b0;
    *reinterpret_cast<float4*>(&Bs[br][bc+4]) = b1;
    __syncthreads();
    #pragma unroll
    for (int kk=0; kk<16; kk++){
      float4 av0 = *reinterpret_cast<float4*>(&As[kk][ty*4]);
      float4 bv0 = *reinterpret_cast<float4*>(&Bs[kk][tx*4]);
      float4 bv1 = *reinterpret_cast<float4*>(&Bs[kk][64+tx*4]);
      float a[4] = {av0.x,av0.y,av0.z,av0.w};
      float b[8] = {bv0.x,bv0.y,bv0.z,bv0.w, bv1.x,bv1.y,bv1.z,bv1.w};
      #pragma unroll
      for (int i=0;i<4;i++)
        #pragma unroll
        for (int j=0;j<8;j++)
          acc[i][j] += a[i]*b[j];
    }
    __syncthreads();
  }
  #pragma unroll
  for (int i=0;i<4;i++){
    int row = bm + ty*4 + i;
    if (row < M){
      float* cp = C + (size_t)row*N + bn;
      *reinterpret_cast<float4*>(cp + tx*4)    = make_float4(acc[i][0],acc[i][1],acc[i][2],acc[i][3]);
      *reinterpret_cast<float4*>(cp + 64+tx*4) = make_float4(acc[i][4],acc[i][5],acc[i][6],acc[i][7]);
    }
  }
}

// ============== per-node attention logits s,d = <h, a_src/a_dst> ============
template<int H, int C>
__global__ void sd_kernel(const float* __restrict__ h, const float* __restrict__ asrc,
                          const float* __restrict__ adst, float* __restrict__ s,
                          float* __restrict__ d, int n_nodes){
  int wave = threadIdx.x >> 6, lane = threadIdx.x & 63;
  int n = blockIdx.x*4 + wave;
  if (n >= n_nodes) return;
  const float* hn = h + (size_t)n*H*C;
  #pragma unroll
  for (int hd=0; hd<H; ++hd){
    float ps=0.f, pd=0.f;
    for (int c=lane; c<C; c+=64){
      float v = hn[hd*C+c];
      ps += v*asrc[hd*C+c];
      pd += v*adst[hd*C+c];
    }
    #pragma unroll
    for (int off=32; off; off>>=1){ ps += __shfl_down(ps,off); pd += __shfl_down(pd,off); }
    if (lane==0){ s[n*H+hd]=ps; d[n*H+hd]=pd; }
  }
}

// ================= GAT aggregation: softmax over in-edges ====================
// One block per dst node, 4 waves. Phase 1: per-head max. Phase 2: wave w
// gathers edges j%4==w with float4/float2 vector loads (VEC=HC/64 channels
// per lane); per-wave partials combined via LDS. Weights computed by wave 0.
template<int H, int C>
__global__ __launch_bounds__(256) void agg_kernel(
    const float* __restrict__ hbuf, const float* __restrict__ s,
    const float* __restrict__ d, const int* __restrict__ offs,
    const int* __restrict__ csr, const float* __restrict__ bias,
    float* __restrict__ y, int n_nodes){
  constexpr int HC = H*C;
  constexpr int VEC = HC/64;            // 4 (H=4,C=64) or 2 (H=1,C=128)
  int n = blockIdx.x;
  int tid = threadIdx.x;
  int wave = tid>>6, lane = tid&63;
  __shared__ float sdst[H];
  __shared__ float sm[H];
  __shared__ float sl[H];
  __shared__ float wred[4*H];
  __shared__ float sw[64*H];
  __shared__ int ssrc[64];
  __shared__ float facc[4][HC];
  if (tid < H) sdst[tid] = d[n*H+tid];
  int start = offs[n];
  int cnt = offs[n+1]-start;
  int cnt1 = cnt+1;                      // + self loop
  __syncthreads();
  // ---- phase 1: per-head max of leakyrelu(s[src]+d[dst])
  float mx[H];
  #pragma unroll
  for (int h=0;h<H;h++) mx[h] = -1e30f;
  for (int i=tid; i<cnt1; i+=256){
    int src = (i==cnt) ? n : csr[start+i];
    if (H == 4){
      float4 sv = *reinterpret_cast<const float4*>(s + (size_t)src*4);
      float ev[4] = {sv.x, sv.y, sv.z, sv.w};
      #pragma unroll
      for (int h=0;h<4;h++){
        float e = ev[h] + sdst[h];
        e = e>=0.f ? e : NEG_SLOPE*e;
        mx[h] = fmaxf(mx[h], e);
      }
    } else {
      float e = s[src] + sdst[0];
      e = e>=0.f ? e : NEG_SLOPE*e;
      mx[0] = fmaxf(mx[0], e);
    }
  }
  #pragma unroll
  for (int off=32; off; off>>=1)
    #pragma unroll
    for (int h=0;h<H;h++) mx[h] = fmaxf(mx[h], __shfl_down(mx[h],off));
  if (lane==0)
    #pragma unroll
    for (int h=0;h<H;h++) wred[wave*H+h]=mx[h];
  __syncthreads();
  if (tid < H){
    float m = wred[tid];
    for (int w=1;w<4;w++) m = fmaxf(m, wred[w*H+tid]);
    sm[tid]=m;
  }
  __syncthreads();
  // ---- phase 2: weighted gather, vectorized + wave-split
  float acc[VEC] = {};
  float lp[H];
  #pragma unroll
  for (int h=0;h<H;h++) lp[h]=0.f;
  for (int base=0; base<cnt1; base+=64){
    int nchunk = min(64, cnt1-base);
    if (tid < nchunk){
      int i = base+tid;
      int src = (i==cnt) ? n : csr[start+i];
      ssrc[tid]=src;
      if (H == 4){
        float4 sv = *reinterpret_cast<const float4*>(s + (size_t)src*4);
        float ev[4] = {sv.x, sv.y, sv.z, sv.w};
        #pragma unroll
        for (int h=0;h<4;h++){
          float e = ev[h] + sdst[h];
          e = e>=0.f ? e : NEG_SLOPE*e;
          float w = expf(e - sm[h]);
          sw[tid*4+h]=w;
          lp[h]+=w;
        }
      } else {
        float e = s[src] + sdst[0];
        e = e>=0.f ? e : NEG_SLOPE*e;
        float w = expf(e - sm[0]);
        sw[tid]=w;
        lp[0]+=w;
      }
    }
    __syncthreads();
    for (int j=wave; j<nchunk; j+=4){
      int src = ssrc[j];
      const float* hp = hbuf + (size_t)src*HC + lane*VEC;
      if (VEC == 4){
        float wt = sw[j*H + (lane>>4)];       // head = lane*4/64
        float4 hv = *reinterpret_cast<const float4*>(hp);
        acc[0]+=wt*hv.x; acc[1]+=wt*hv.y; acc[2]+=wt*hv.z; acc[3]+=wt*hv.w;
      } else {
        float wt = sw[j];                     // H==1
        float2 hv = *reinterpret_cast<const float2*>(hp);
        acc[0]+=wt*hv.x; acc[1]+=wt*hv.y;
      }
    }
    __syncthreads();
  }
  // lp lives only in wave 0 (tid<nchunk<=64)
  if (wave==0){
    #pragma unroll
    for (int off=32; off; off>>=1)
      #pragma unroll
      for (int h=0;h<H;h++) lp[h] += __shfl_down(lp[h],off);
    if (lane==0)
      #pragma unroll
      for (int h=0;h<H;h++) sl[h]=lp[h];
  }
  #pragma unroll
  for (int v=0;v<VEC;v++) facc[wave][lane*VEC+v] = acc[v];
  __syncthreads();
  if (tid < HC){
    float a = facc[0][tid]+facc[1][tid]+facc[2][tid]+facc[3][tid];
    int head = tid / C;
    float o = a/(sl[head]+1e-16f) + bias[tid];
    y[(size_t)n*HC+tid] = o>0.f ? o : expm1f(o);
  }
}

// ======================= Set2Set, grid-parallel =============================
__global__ __launch_bounds__(256) void e_kernel(
    const float* __restrict__ x, const float* __restrict__ q,
    const int* __restrict__ batch, float* __restrict__ e,
    unsigned* __restrict__ menc, int N){
  int tid = threadIdx.x;
  int wave = tid>>6, lane = tid&63;
  int base = blockIdx.x*16;
  __shared__ unsigned lm[64];
  if (tid < 64) lm[tid] = 0u;
  __syncthreads();
  #pragma unroll
  for (int j=0;j<4;j++){
    int i = base + wave*4 + j;
    if (i < N){
      int g = batch[i];
      float2 xv = *reinterpret_cast<const float2*>(x + (size_t)i*128 + lane*2);
      float2 qv = *reinterpret_cast<const float2*>(q + (size_t)g*128 + lane*2);
      float p = xv.x*qv.x + xv.y*qv.y;
      #pragma unroll
      for (int off=32; off; off>>=1) p += __shfl_down(p, off);
      if (lane==0){
        e[i] = p;
        atomicMax(&lm[g], fenc(p));
      }
    }
  }
  __syncthreads();
  if (tid < 64 && lm[tid]) atomicMax(&menc[tid], lm[tid]);
}

__global__ __launch_bounds__(128) void racc_kernel(
    const float* __restrict__ x, const float* __restrict__ e,
    const int* __restrict__ batch, const unsigned* __restrict__ menc,
    float* __restrict__ rsum, float* __restrict__ lsum, int N){
  int col = threadIdx.x;
  int c0 = blockIdx.x*32;
  int endi = min(c0+32, N);
  if (c0 >= N) return;
  int curg = batch[c0];
  float m = fdec(menc[curg]);
  float acc = 0.f, lacc = 0.f;
  for (int i=c0; i<endi; ++i){
    int g = batch[i];
    if (g != curg){
      atomicAdd(&rsum[curg*128+col], acc);
      if (col==0) atomicAdd(&lsum[curg], lacc);
      acc = 0.f; lacc = 0.f; curg = g; m = fdec(menc[g]);
    }
    float w = expf(e[i]-m);
    acc += w * x[(size_t)i*128+col];
    lacc += w;
  }
  atomicAdd(&rsum[curg*128+col], acc);
  if (col==0) atomicAdd(&lsum[curg], lacc);
}

template<int STEP>
__global__ __launch_bounds__(256) void s2s_step_kernel(
    const float* __restrict__ rsum, const float* __restrict__ lsum,
    float* __restrict__ hc, float* __restrict__ qbuf,
    const float* __restrict__ Wih, const float* __restrict__ Whh,
    const float* __restrict__ bih, const float* __restrict__ bhh,
    const float* __restrict__ gfeat,
    const float* __restrict__ gW1, const float* __restrict__ gb1,
    const float* __restrict__ gW2, const float* __restrict__ gb2,
    const float* __restrict__ mW1, const float* __restrict__ mb1,
    const float* __restrict__ mW2, const float* __restrict__ mb2,
    float* __restrict__ out, int B){
  int b = blockIdx.x, tid = threadIdx.x;
  __shared__ float qs[256];

  if (STEP > 0){
    if (tid < 128){
      const float* rs = rsum + (size_t)(STEP-1)*B*128 + (size_t)b*128;
      float ls = lsum[(STEP-1)*B + b];
      qs[tid]     = qbuf[b*128+tid];
      qs[128+tid] = rs[tid] / (ls + 1e-16f);
    }
    __syncthreads();
  }

  if (STEP < 3){
    __shared__ float hs[128], gsh[512];
    if (STEP > 0){ if (tid<128) hs[tid] = hc[(size_t)b*128+tid]; }
    __syncthreads();
    #pragma unroll
    for (int p=0;p<2;p++){
      int j = tid + p*256;
      float a = bih[j] + bhh[j];
      if (STEP > 0){
        const float* wi = Wih + (size_t)j*256;
        for (int k=0;k<256;k+=4)
          a += qs[k]*wi[k] + qs[k+1]*wi[k+1] + qs[k+2]*wi[k+2] + qs[k+3]*wi[k+3];
        const float* wh = Whh + (size_t)j*128;
        for (int k=0;k<128;k+=4)
          a += hs[k]*wh[k] + hs[k+1]*wh[k+1] + hs[k+2]*wh[k+2] + hs[k+3]*wh[k+3];
      }
      gsh[j] = a;
    }
    __syncthreads();
    if (tid < 128){
      float cprev = (STEP==0) ? 0.f : hc[(size_t)(B+b)*128+tid];
      float ig = sigmoidf(gsh[tid]);
      float fg = sigmoidf(gsh[128+tid]);
      float gg = tanhf(gsh[256+tid]);
      float og = sigmoidf(gsh[384+tid]);
      float c2 = fg*cprev + ig*gg;
      float h2 = og*tanhf(c2);
      hc[(size_t)b*128+tid] = h2;
      hc[(size_t)(B+b)*128+tid] = c2;
      qbuf[b*128+tid] = h2;
    }
  } else {
    __shared__ float z[288], gf1[64], hid[128];
    z[tid] = qs[tid];
    if (tid < 64){
      float a = gb1[tid];
      for (int k=0;k<9;k++) a += gfeat[b*9+k]*gW1[k*64+tid];
      gf1[tid] = a>0.f ? a : 0.f;
    }
    __syncthreads();
    if (tid < 32){
      float a = gb2[tid];
      for (int k=0;k<64;k++) a += gf1[k]*gW2[k*32+tid];
      z[256+tid] = a;
    }
    __syncthreads();
    if (tid < 128){
      float a = mb1[tid];
      for (int k=0;k<288;k++) a += z[k]*mW1[(size_t)k*128+tid];
      hid[tid] = a>0.f ? a : 0.f;
    }
    __syncthreads();
    if (tid < 4){
      float a = mb2[tid];
      for (int k=0;k<128;k++) a += hid[k]*mW2[k*4+tid];
      out[b*4+tid] = a;
    }
  }
}

// ================================ launch ====================================
extern "C" void kernel_launch(void* const* d_in, const int* in_sizes, int n_in,
                              void* d_out, int out_size, void* d_ws, size_t ws_size,
                              hipStream_t stream) {
  const float* x     = (const float*)d_in[0];
  const int*   ei    = (const int*)d_in[1];
  const int*   batch = (const int*)d_in[2];
  const float* gfeat = (const float*)d_in[3];
  const float* W1    = (const float*)d_in[4];
  const float* as1   = (const float*)d_in[5];
  const float* ad1   = (const float*)d_in[6];
  const float* b1    = (const float*)d_in[7];
  const float* W2    = (const float*)d_in[8];
  const float* as2   = (const float*)d_in[9];
  const float* ad2   = (const float*)d_in[10];
  const float* b2    = (const float*)d_in[11];
  const float* W3    = (const float*)d_in[12];
  const float* as3   = (const float*)d_in[13];
  const float* ad3   = (const float*)d_in[14];
  const float* b3    = (const float*)d_in[15];
  const float* Wih   = (const float*)d_in[16];
  const float* Whh   = (const float*)d_in[17];
  const float* bih   = (const float*)d_in[18];
  const float* bhh   = (const float*)d_in[19];
  const float* gW1   = (const float*)d_in[20];
  const float* gb1   = (const float*)d_in[21];
  const float* gW2   = (const float*)d_in[22];
  const float* gb2   = (const float*)d_in[23];
  const float* mW1   = (const float*)d_in[24];
  const float* mb1   = (const float*)d_in[25];
  const float* mW2   = (const float*)d_in[26];
  const float* mb2   = (const float*)d_in[27];

  const int N = in_sizes[0]/128;   // 20000
  const int E = in_sizes[1]/2;     // 320000
  const int B = in_sizes[3]/9;     // 64

  char* ws = (char*)d_ws;
  size_t off = 0;
  auto alloc = [&](size_t bytes)->char*{
    char* p = ws + off;
    off += (bytes + 255) & ~(size_t)255;
    return p;
  };
  float* hbuf   = (float*)alloc((size_t)N*256*4);
  float* ybuf1  = (float*)alloc((size_t)N*256*4);
  float* ybuf2  = (float*)alloc((size_t)N*256*4);
  float* sbuf   = (float*)alloc((size_t)N*4*4);
  float* dbuf   = (float*)alloc((size_t)N*4*4);
  float* e_ws   = (float*)alloc((size_t)N*4);
  int*   counts = (int*)alloc((size_t)N*4);
  int*   offs   = (int*)alloc((size_t)(N+1)*4);
  int*   cursor = (int*)alloc((size_t)N*4);
  int*   csr    = (int*)alloc((size_t)E*4);
  int*   gstart = (int*)alloc((size_t)B*4);
  int*   gend   = (int*)alloc((size_t)B*4);
  float* hcbuf  = (float*)alloc((size_t)2*B*128*4);
  float* qbuf   = (float*)alloc((size_t)B*128*4);
  float* rsum   = (float*)alloc((size_t)3*B*128*4);
  float* lsum   = (float*)alloc((size_t)3*B*4);
  unsigned* menc= (unsigned*)alloc((size_t)3*B*4);

  int nInit = max(N, 3*B*128);
  init_kernel<<<(nInit+255)/256, 256, 0, stream>>>(counts, gstart, gend,
                                                   rsum, lsum, menc, N, B);
  int gridEN = (max(E,N)+255)/256;
  build_kernel<<<gridEN, 256, 0, stream>>>(ei, batch, counts, gstart, gend, E, N);
  scan_kernel<<<1, 1024, 0, stream>>>(counts, offs, cursor, N);
  fill_kernel<<<(E+255)/256, 256, 0, stream>>>(ei, cursor, csr, E);

  int gm = (N+63)/64;
  // ---- layer 1: x[N,128] -> h[N,256] -> y1
  gemm64x128<<<dim3(gm,2), 256, 0, stream>>>(x, W1, hbuf, N, 128, 256);
  sd_kernel<4,64><<<(N+3)/4, 256, 0, stream>>>(hbuf, as1, ad1, sbuf, dbuf, N);
  agg_kernel<4,64><<<N, 256, 0, stream>>>(hbuf, sbuf, dbuf, offs, csr, b1, ybuf1, N);
  // ---- layer 2: y1[N,256] -> h[N,256] -> y2
  gemm64x128<<<dim3(gm,2), 256, 0, stream>>>(ybuf1, W2, hbuf, N, 256, 256);
  sd_kernel<4,64><<<(N+3)/4, 256, 0, stream>>>(hbuf, as2, ad2, sbuf, dbuf, N);
  agg_kernel<4,64><<<N, 256, 0, stream>>>(hbuf, sbuf, dbuf, offs, csr, b2, ybuf2, N);
  // ---- layer 3: y2[N,256] -> h[N,128] -> y1 (reuse)
  gemm64x128<<<dim3(gm,1), 256, 0, stream>>>(ybuf2, W3, hbuf, N, 256, 128);
  sd_kernel<1,128><<<(N+3)/4, 256, 0, stream>>>(hbuf, as3, ad3, sbuf, dbuf, N);
  agg_kernel<1,128><<<N, 256, 0, stream>>>(hbuf, sbuf, dbuf, offs, csr, b3, ybuf1, N);

  // ---- set2set (grid-parallel readout) + scorer ----
  int ge = (N+15)/16;
  int gr = (N+31)/32;
  s2s_step_kernel<0><<<B, 256, 0, stream>>>(rsum, lsum, hcbuf, qbuf,
      Wih, Whh, bih, bhh, gfeat, gW1, gb1, gW2, gb2, mW1, mb1, mW2, mb2, (float*)d_out, B);
  e_kernel<<<ge, 256, 0, stream>>>(ybuf1, qbuf, batch, e_ws, menc + 0*B, N);
  racc_kernel<<<gr, 128, 0, stream>>>(ybuf1, e_ws, batch, menc + 0*B, rsum + 0*(size_t)B*128, lsum + 0*B, N);
  s2s_step_kernel<1><<<B, 256, 0, stream>>>(rsum, lsum, hcbuf, qbuf,
      Wih, Whh, bih, bhh, gfeat, gW1, gb1, gW2, gb2, mW1, mb1, mW2, mb2, (float*)d_out, B);
  e_kernel<<<ge, 256, 0, stream>>>(ybuf1, qbuf, batch, e_ws, menc + 1*B, N);
  racc_kernel<<<gr, 128, 0, stream>>>(ybuf1, e_ws, batch, menc + 1*B, rsum + 1*(size_t)B*128, lsum + 1*B, N);
  s2s_step_kernel<2><<<B, 256, 0, stream>>>(rsum, lsum, hcbuf, qbuf,
      Wih, Whh, bih, bhh, gfeat, gW1, gb1, gW2, gb2, mW1, mb1, mW2, mb2, (float*)d_out, B);
  e_kernel<<<ge, 256, 0, stream>>>(ybuf1, qbuf, batch, e_ws, menc + 2*B, N);
  racc_kernel<<<gr, 128, 0, stream>>>(ybuf1, e_ws, batch, menc + 2*B, rsum + 2*(size_t)B*128, lsum + 2*B, N);
  s2s_step_kernel<3><<<B, 256, 0, stream>>>(rsum, lsum, hcbuf, qbuf,
      Wih, Whh, bih, bhh, gfeat, gW1, gb1, gW2, gb2, mW1, mb1, mW2, mb2, (float*)d_out, B);
}

// Round 6
// 551.510 us; speedup vs baseline: 1.4854x; 1.1110x over previous
//
#include <hip/hip_runtime.h>
#include <hip/hip_bf16.h>
#include <math.h>

#define NEG_SLOPE 0.2f

__device__ __forceinline__ float sigmoidf(float x){ return 1.f/(1.f+expf(-x)); }

// ============================ init + CSR build ==============================
__global__ void init_kernel(int* counts, int* gstart, int* gend,
                            float* rsum, float* lsum, int n, int b){
  int i = blockIdx.x*blockDim.x + threadIdx.x;
  if (i < n) counts[i] = 0;
  if (i < b){ gstart[i] = 0; gend[i] = 0; }
  if (i < 3*b*128) rsum[i] = 0.f;
  if (i < 3*b) lsum[i] = 0.f;
}

// counts via atomics (16-way mean contention); graph bounds via sorted-batch
// boundary detection (NO atomics - 64-address atomicMin/Max chains were 122us).
__global__ void build_kernel(const int* __restrict__ ei, const int* __restrict__ batch,
                             int* counts, int* gstart, int* gend, int E, int n){
  int i = blockIdx.x*blockDim.x + threadIdx.x;
  if (i < E) atomicAdd(&counts[ei[E+i]], 1);
  if (i < n){
    int b = batch[i];
    if (i == 0 || batch[i-1] != b) gstart[b] = i;
    if (i == n-1 || batch[i+1] != b) gend[b] = i+1;
  }
}

__global__ void scan_kernel(const int* __restrict__ counts, int* offs, int* cursor, int n){
  const int T = 1024;
  int tid = threadIdx.x;
  int chunk = (n + T - 1)/T;
  int base = tid*chunk;
  int local = 0;
  for (int i=0;i<chunk;i++){ int idx=base+i; if (idx<n) local += counts[idx]; }
  __shared__ int ss[T];
  ss[tid]=local; __syncthreads();
  for (int off=1; off<T; off<<=1){
    int v = (tid>=off)? ss[tid-off] : 0;
    __syncthreads();
    ss[tid]+=v;
    __syncthreads();
  }
  int run = ss[tid]-local;  // exclusive prefix
  for (int i=0;i<chunk;i++){
    int idx=base+i;
    if (idx<n){ offs[idx]=run; cursor[idx]=run; run += counts[idx]; }
  }
  if (tid==T-1) offs[n]=run;
}

__global__ void fill_kernel(const int* __restrict__ ei, int* cursor, int* csr, int E){
  int i = blockIdx.x*blockDim.x + threadIdx.x;
  if (i<E){
    int dst = ei[E+i];
    int pos = atomicAdd(&cursor[dst],1);
    csr[pos] = ei[i];
  }
}

// ============================ fp32 tiled GEMM ===============================
__global__ __launch_bounds__(256) void gemm64x128(const float* __restrict__ A,
                                                  const float* __restrict__ B,
                                                  float* __restrict__ C,
                                                  int M, int K, int N){
  __shared__ float As[16][64];
  __shared__ float Bs[16][128];
  int tid = threadIdx.x;
  int bm = blockIdx.x*64, bn = blockIdx.y*128;
  int ar = tid>>2, ak=(tid&3)*4;
  int br = tid>>4, bc=(tid&15)*8;
  int ty = tid>>4, tx = tid&15;
  float acc[4][8] = {};
  for (int k0=0; k0<K; k0+=16){
    float4 av = make_float4(0,0,0,0);
    if (bm+ar < M) av = *reinterpret_cast<const float4*>(A + (size_t)(bm+ar)*K + k0 + ak);
    const float* bp = B + (size_t)(k0+br)*N + bn + bc;
    float4 b0 = *reinterpret_cast<const float4*>(bp);
    float4 b1 = *reinterpret_cast<const float4*>(bp+4);
    As[ak+0][ar]=av.x; As[ak+1][ar]=av.y; As[ak+2][ar]=av.z; As[ak+3][ar]=av.w;
    *reinterpret_cast<float4*>(&Bs[br][bc])   = b0;
    *reinterpret_cast<float4*>(&Bs[br][bc+4]) = b1;
    __syncthreads();
    #pragma unroll
    for (int kk=0; kk<16; kk++){
      float4 av0 = *reinterpret_cast<float4*>(&As[kk][ty*4]);
      float4 bv0 = *reinterpret_cast<float4*>(&Bs[kk][tx*4]);
      float4 bv1 = *reinterpret_cast<float4*>(&Bs[kk][64+tx*4]);
      float a[4] = {av0.x,av0.y,av0.z,av0.w};
      float b[8] = {bv0.x,bv0.y,bv0.z,bv0.w, bv1.x,bv1.y,bv1.z,bv1.w};
      #pragma unroll
      for (int i=0;i<4;i++)
        #pragma unroll
        for (int j=0;j<8;j++)
          acc[i][j] += a[i]*b[j];
    }
    __syncthreads();
  }
  #pragma unroll
  for (int i=0;i<4;i++){
    int row = bm + ty*4 + i;
    if (row < M){
      float* cp = C + (size_t)row*N + bn;
      *reinterpret_cast<float4*>(cp + tx*4)    = make_float4(acc[i][0],acc[i][1],acc[i][2],acc[i][3]);
      *reinterpret_cast<float4*>(cp + 64+tx*4) = make_float4(acc[i][4],acc[i][5],acc[i][6],acc[i][7]);
    }
  }
}

// ============== per-node attention logits s,d = <h, a_src/a_dst> ============
template<int H, int C>
__global__ void sd_kernel(const float* __restrict__ h, const float* __restrict__ asrc,
                          const float* __restrict__ adst, float* __restrict__ s,
                          float* __restrict__ d, int n_nodes){
  int wave = threadIdx.x >> 6, lane = threadIdx.x & 63;
  int n = blockIdx.x*4 + wave;
  if (n >= n_nodes) return;
  const float* hn = h + (size_t)n*H*C;
  #pragma unroll
  for (int hd=0; hd<H; ++hd){
    float ps=0.f, pd=0.f;
    for (int c=lane; c<C; c+=64){
      float v = hn[hd*C+c];
      ps += v*asrc[hd*C+c];
      pd += v*adst[hd*C+c];
    }
    #pragma unroll
    for (int off=32; off; off>>=1){ ps += __shfl_down(ps,off); pd += __shfl_down(pd,off); }
    if (lane==0){ s[n*H+hd]=ps; d[n*H+hd]=pd; }
  }
}

// ================= GAT aggregation: softmax over in-edges ====================
// One block per dst node, 4 waves. Softmax WITHOUT max-subtraction (shift
// invariant; |e| is O(few) so exp can't overflow fp32). Weights computed in
// one pass; wave w gathers edges j%4==w with float4/float2 vector loads.
template<int H, int C>
__global__ __launch_bounds__(256) void agg_kernel(
    const float* __restrict__ hbuf, const float* __restrict__ s,
    const float* __restrict__ d, const int* __restrict__ offs,
    const int* __restrict__ csr, const float* __restrict__ bias,
    float* __restrict__ y, int n_nodes){
  constexpr int HC = H*C;
  constexpr int VEC = HC/64;            // 4 (H=4,C=64) or 2 (H=1,C=128)
  int n = blockIdx.x;
  int tid = threadIdx.x;
  int wave = tid>>6, lane = tid&63;
  __shared__ float sdst[H];
  __shared__ float sl[H];
  __shared__ float sw[64*H];
  __shared__ int ssrc[64];
  __shared__ float facc[4][HC];
  if (tid < H) sdst[tid] = d[n*H+tid];
  int start = offs[n];
  int cnt = offs[n+1]-start;
  int cnt1 = cnt+1;                      // + self loop
  __syncthreads();
  float acc[VEC] = {};
  float lp[H];
  #pragma unroll
  for (int h=0;h<H;h++) lp[h]=0.f;
  for (int base=0; base<cnt1; base+=64){
    int nchunk = min(64, cnt1-base);
    if (tid < nchunk){
      int i = base+tid;
      int src = (i==cnt) ? n : csr[start+i];
      ssrc[tid]=src;
      if (H == 4){
        float4 sv = *reinterpret_cast<const float4*>(s + (size_t)src*4);
        float ev[4] = {sv.x, sv.y, sv.z, sv.w};
        #pragma unroll
        for (int h=0;h<4;h++){
          float e = ev[h] + sdst[h];
          e = e>=0.f ? e : NEG_SLOPE*e;
          float w = expf(e);
          sw[tid*4+h]=w;
          lp[h]+=w;
        }
      } else {
        float e = s[src] + sdst[0];
        e = e>=0.f ? e : NEG_SLOPE*e;
        float w = expf(e);
        sw[tid]=w;
        lp[0]+=w;
      }
    }
    __syncthreads();
    for (int j=wave; j<nchunk; j+=4){
      int src = ssrc[j];
      const float* hp = hbuf + (size_t)src*HC + lane*VEC;
      if (VEC == 4){
        float wt = sw[j*H + (lane>>4)];       // head = lane*4/64
        float4 hv = *reinterpret_cast<const float4*>(hp);
        acc[0]+=wt*hv.x; acc[1]+=wt*hv.y; acc[2]+=wt*hv.z; acc[3]+=wt*hv.w;
      } else {
        float wt = sw[j];                     // H==1
        float2 hv = *reinterpret_cast<const float2*>(hp);
        acc[0]+=wt*hv.x; acc[1]+=wt*hv.y;
      }
    }
    __syncthreads();
  }
  // lp lives only in wave 0 (tid<nchunk<=64)
  if (wave==0){
    #pragma unroll
    for (int off=32; off; off>>=1)
      #pragma unroll
      for (int h=0;h<H;h++) lp[h] += __shfl_down(lp[h],off);
    if (lane==0)
      #pragma unroll
      for (int h=0;h<H;h++) sl[h]=lp[h];
  }
  #pragma unroll
  for (int v=0;v<VEC;v++) facc[wave][lane*VEC+v] = acc[v];
  __syncthreads();
  if (tid < HC){
    float a = facc[0][tid]+facc[1][tid]+facc[2][tid]+facc[3][tid];
    int head = tid / C;
    float o = a/(sl[head]+1e-16f) + bias[tid];
    y[(size_t)n*HC+tid] = o>0.f ? o : expm1f(o);
  }
}

// ======================= Set2Set, grid-parallel =============================
// Fused readout (no max needed without shift): block covers 32 contiguous
// (sorted) nodes. Phase A: 4 waves compute w_i = exp(<x_i, q[batch_i]>) into
// LDS. Phase B: 128 col-threads accumulate rsum/lsum with per-run atomics.
__global__ __launch_bounds__(256) void read_kernel(
    const float* __restrict__ x, const float* __restrict__ q,
    const int* __restrict__ batch,
    float* __restrict__ rsum, float* __restrict__ lsum, int N){
  int tid = threadIdx.x;
  int wave = tid>>6, lane = tid&63;
  int c0 = blockIdx.x*32;
  if (c0 >= N) return;
  __shared__ float ws[32];
  __shared__ int gb[32];
  if (tid < 32 && c0+tid < N) gb[tid] = batch[c0+tid];
  __syncthreads();
  #pragma unroll
  for (int j=0;j<8;j++){
    int k = wave*8 + j;
    int i = c0 + k;
    if (i < N){
      int g = gb[k];
      float2 xv = *reinterpret_cast<const float2*>(x + (size_t)i*128 + lane*2);
      float2 qv = *reinterpret_cast<const float2*>(q + (size_t)g*128 + lane*2);
      float p = xv.x*qv.x + xv.y*qv.y;
      #pragma unroll
      for (int off=32; off; off>>=1) p += __shfl_down(p, off);
      if (lane==0) ws[k] = expf(p);
    }
  }
  __syncthreads();
  if (tid < 128){
    int col = tid;
    int endi = min(c0+32, N);
    int curg = gb[0];
    float acc = 0.f, lacc = 0.f;
    for (int i=c0; i<endi; ++i){
      int g = gb[i-c0];
      if (g != curg){
        atomicAdd(&rsum[curg*128+col], acc);
        if (col==0) atomicAdd(&lsum[curg], lacc);
        acc = 0.f; lacc = 0.f; curg = g;
      }
      float w = ws[i-c0];
      acc += w * x[(size_t)i*128+col];
      lacc += w;
    }
    atomicAdd(&rsum[curg*128+col], acc);
    if (col==0) atomicAdd(&lsum[curg], lacc);
  }
}

template<int STEP>
__global__ __launch_bounds__(256) void s2s_step_kernel(
    const float* __restrict__ rsum, const float* __restrict__ lsum,
    float* __restrict__ hc, float* __restrict__ qbuf,
    const float* __restrict__ Wih, const float* __restrict__ Whh,
    const float* __restrict__ bih, const float* __restrict__ bhh,
    const float* __restrict__ gfeat,
    const float* __restrict__ gW1, const float* __restrict__ gb1,
    const float* __restrict__ gW2, const float* __restrict__ gb2,
    const float* __restrict__ mW1, const float* __restrict__ mb1,
    const float* __restrict__ mW2, const float* __restrict__ mb2,
    float* __restrict__ out, int B){
  int b = blockIdx.x, tid = threadIdx.x;
  __shared__ float qs[256];

  if (STEP > 0){
    if (tid < 128){
      const float* rs = rsum + (size_t)(STEP-1)*B*128 + (size_t)b*128;
      float ls = lsum[(STEP-1)*B + b];
      qs[tid]     = qbuf[b*128+tid];
      qs[128+tid] = rs[tid] / (ls + 1e-16f);
    }
    __syncthreads();
  }

  if (STEP < 3){
    __shared__ float hs[128], gsh[512];
    if (STEP > 0){ if (tid<128) hs[tid] = hc[(size_t)b*128+tid]; }
    __syncthreads();
    #pragma unroll
    for (int p=0;p<2;p++){
      int j = tid + p*256;
      float a = bih[j] + bhh[j];
      if (STEP > 0){
        const float* wi = Wih + (size_t)j*256;
        for (int k=0;k<256;k+=4)
          a += qs[k]*wi[k] + qs[k+1]*wi[k+1] + qs[k+2]*wi[k+2] + qs[k+3]*wi[k+3];
        const float* wh = Whh + (size_t)j*128;
        for (int k=0;k<128;k+=4)
          a += hs[k]*wh[k] + hs[k+1]*wh[k+1] + hs[k+2]*wh[k+2] + hs[k+3]*wh[k+3];
      }
      gsh[j] = a;
    }
    __syncthreads();
    if (tid < 128){
      float cprev = (STEP==0) ? 0.f : hc[(size_t)(B+b)*128+tid];
      float ig = sigmoidf(gsh[tid]);
      float fg = sigmoidf(gsh[128+tid]);
      float gg = tanhf(gsh[256+tid]);
      float og = sigmoidf(gsh[384+tid]);
      float c2 = fg*cprev + ig*gg;
      float h2 = og*tanhf(c2);
      hc[(size_t)b*128+tid] = h2;
      hc[(size_t)(B+b)*128+tid] = c2;
      qbuf[b*128+tid] = h2;
    }
  } else {
    __shared__ float z[288], gf1[64], hid[128];
    z[tid] = qs[tid];
    if (tid < 64){
      float a = gb1[tid];
      for (int k=0;k<9;k++) a += gfeat[b*9+k]*gW1[k*64+tid];
      gf1[tid] = a>0.f ? a : 0.f;
    }
    __syncthreads();
    if (tid < 32){
      float a = gb2[tid];
      for (int k=0;k<64;k++) a += gf1[k]*gW2[k*32+tid];
      z[256+tid] = a;
    }
    __syncthreads();
    if (tid < 128){
      float a = mb1[tid];
      for (int k=0;k<288;k++) a += z[k]*mW1[(size_t)k*128+tid];
      hid[tid] = a>0.f ? a : 0.f;
    }
    __syncthreads();
    if (tid < 4){
      float a = mb2[tid];
      for (int k=0;k<128;k++) a += hid[k]*mW2[k*4+tid];
      out[b*4+tid] = a;
    }
  }
}

// ================================ launch ====================================
extern "C" void kernel_launch(void* const* d_in, const int* in_sizes, int n_in,
                              void* d_out, int out_size, void* d_ws, size_t ws_size,
                              hipStream_t stream) {
  const float* x     = (const float*)d_in[0];
  const int*   ei    = (const int*)d_in[1];
  const int*   batch = (const int*)d_in[2];
  const float* gfeat = (const float*)d_in[3];
  const float* W1    = (const float*)d_in[4];
  const float* as1   = (const float*)d_in[5];
  const float* ad1   = (const float*)d_in[6];
  const float* b1    = (const float*)d_in[7];
  const float* W2    = (const float*)d_in[8];
  const float* as2   = (const float*)d_in[9];
  const float* ad2   = (const float*)d_in[10];
  const float* b2    = (const float*)d_in[11];
  const float* W3    = (const float*)d_in[12];
  const float* as3   = (const float*)d_in[13];
  const float* ad3   = (const float*)d_in[14];
  const float* b3    = (const float*)d_in[15];
  const float* Wih   = (const float*)d_in[16];
  const float* Whh   = (const float*)d_in[17];
  const float* bih   = (const float*)d_in[18];
  const float* bhh   = (const float*)d_in[19];
  const float* gW1   = (const float*)d_in[20];
  const float* gb1   = (const float*)d_in[21];
  const float* gW2   = (const float*)d_in[22];
  const float* gb2   = (const float*)d_in[23];
  const float* mW1   = (const float*)d_in[24];
  const float* mb1   = (const float*)d_in[25];
  const float* mW2   = (const float*)d_in[26];
  const float* mb2   = (const float*)d_in[27];

  const int N = in_sizes[0]/128;   // 20000
  const int E = in_sizes[1]/2;     // 320000
  const int B = in_sizes[3]/9;     // 64

  char* ws = (char*)d_ws;
  size_t off = 0;
  auto alloc = [&](size_t bytes)->char*{
    char* p = ws + off;
    off += (bytes + 255) & ~(size_t)255;
    return p;
  };
  float* hbuf   = (float*)alloc((size_t)N*256*4);
  float* ybuf1  = (float*)alloc((size_t)N*256*4);
  float* ybuf2  = (float*)alloc((size_t)N*256*4);
  float* sbuf   = (float*)alloc((size_t)N*4*4);
  float* dbuf   = (float*)alloc((size_t)N*4*4);
  int*   counts = (int*)alloc((size_t)N*4);
  int*   offs   = (int*)alloc((size_t)(N+1)*4);
  int*   cursor = (int*)alloc((size_t)N*4);
  int*   csr    = (int*)alloc((size_t)E*4);
  int*   gstart = (int*)alloc((size_t)B*4);
  int*   gend   = (int*)alloc((size_t)B*4);
  float* hcbuf  = (float*)alloc((size_t)2*B*128*4);
  float* qbuf   = (float*)alloc((size_t)B*128*4);
  float* rsum   = (float*)alloc((size_t)3*B*128*4);
  float* lsum   = (float*)alloc((size_t)3*B*4);

  int nInit = max(N, 3*B*128);
  init_kernel<<<(nInit+255)/256, 256, 0, stream>>>(counts, gstart, gend,
                                                   rsum, lsum, N, B);
  int gridEN = (max(E,N)+255)/256;
  build_kernel<<<gridEN, 256, 0, stream>>>(ei, batch, counts, gstart, gend, E, N);
  scan_kernel<<<1, 1024, 0, stream>>>(counts, offs, cursor, N);
  fill_kernel<<<(E+255)/256, 256, 0, stream>>>(ei, cursor, csr, E);

  int gm = (N+63)/64;
  // ---- layer 1: x[N,128] -> h[N,256] -> y1
  gemm64x128<<<dim3(gm,2), 256, 0, stream>>>(x, W1, hbuf, N, 128, 256);
  sd_kernel<4,64><<<(N+3)/4, 256, 0, stream>>>(hbuf, as1, ad1, sbuf, dbuf, N);
  agg_kernel<4,64><<<N, 256, 0, stream>>>(hbuf, sbuf, dbuf, offs, csr, b1, ybuf1, N);
  // ---- layer 2: y1[N,256] -> h[N,256] -> y2
  gemm64x128<<<dim3(gm,2), 256, 0, stream>>>(ybuf1, W2, hbuf, N, 256, 256);
  sd_kernel<4,64><<<(N+3)/4, 256, 0, stream>>>(hbuf, as2, ad2, sbuf, dbuf, N);
  agg_kernel<4,64><<<N, 256, 0, stream>>>(hbuf, sbuf, dbuf, offs, csr, b2, ybuf2, N);
  // ---- layer 3: y2[N,256] -> h[N,128] -> y1 (reuse)
  gemm64x128<<<dim3(gm,1), 256, 0, stream>>>(ybuf2, W3, hbuf, N, 256, 128);
  sd_kernel<1,128><<<(N+3)/4, 256, 0, stream>>>(hbuf, as3, ad3, sbuf, dbuf, N);
  agg_kernel<1,128><<<N, 256, 0, stream>>>(hbuf, sbuf, dbuf, offs, csr, b3, ybuf1, N);

  // ---- set2set (fused grid-parallel readout) + scorer ----
  int gr = (N+31)/32;
  s2s_step_kernel<0><<<B, 256, 0, stream>>>(rsum, lsum, hcbuf, qbuf,
      Wih, Whh, bih, bhh, gfeat, gW1, gb1, gW2, gb2, mW1, mb1, mW2, mb2, (float*)d_out, B);
  read_kernel<<<gr, 256, 0, stream>>>(ybuf1, qbuf, batch, rsum + 0*(size_t)B*128, lsum + 0*B, N);
  s2s_step_kernel<1><<<B, 256, 0, stream>>>(rsum, lsum, hcbuf, qbuf,
      Wih, Whh, bih, bhh, gfeat, gW1, gb1, gW2, gb2, mW1, mb1, mW2, mb2, (float*)d_out, B);
  read_kernel<<<gr, 256, 0, stream>>>(ybuf1, qbuf, batch, rsum + 1*(size_t)B*128, lsum + 1*B, N);
  s2s_step_kernel<2><<<B, 256, 0, stream>>>(rsum, lsum, hcbuf, qbuf,
      Wih, Whh, bih, bhh, gfeat, gW1, gb1, gW2, gb2, mW1, mb1, mW2, mb2, (float*)d_out, B);
  read_kernel<<<gr, 256, 0, stream>>>(ybuf1, qbuf, batch, rsum + 2*(size_t)B*128, lsum + 2*B, N);
  s2s_step_kernel<3><<<B, 256, 0, stream>>>(rsum, lsum, hcbuf, qbuf,
      Wih, Whh, bih, bhh, gfeat, gW1, gb1, gW2, gb2, mW1, mb1, mW2, mb2, (float*)d_out, B);
}